// Round 1
// baseline (1173.981 us; speedup 1.0000x reference)
//
#include <hip/hip_runtime.h>

typedef unsigned short u16;
typedef __attribute__((ext_vector_type(4))) short bf16x4;
typedef __attribute__((ext_vector_type(8))) short bf16x8;
typedef __attribute__((ext_vector_type(4))) float f32x4;

#define SCALE 0.125f
#define BLENDF 0.4875f
#define NTOT 2202
#define NPAD 2304

__device__ __forceinline__ u16 f2bf(float x){
  union { float f; unsigned u; } v; v.f = x;
  unsigned r = v.u + 0x7fffu + ((v.u >> 16) & 1u);
  return (u16)(r >> 16);
}

__device__ __forceinline__ bf16x8 ldfrag(const u16* p){
  bf16x4 lo = *(const bf16x4*)(p);
  bf16x4 hi = *(const bf16x4*)(p + 16);
  return __builtin_shufflevector(lo, hi, 0,1,2,3,4,5,6,7);
}

__device__ __forceinline__ f32x4 MFMA(bf16x8 a, bf16x8 b, f32x4 c){
  return __builtin_amdgcn_mfma_f32_16x16x32_bf16(a, b, c, 0, 0, 0);
}

__device__ __forceinline__ float red16_sum(float x){
  x += __shfl_xor(x, 1, 64);
  x += __shfl_xor(x, 2, 64);
  x += __shfl_xor(x, 4, 64);
  x += __shfl_xor(x, 8, 64);
  return x;
}
__device__ __forceinline__ float red16_max(float x){
  x = fmaxf(x, __shfl_xor(x, 1, 64));
  x = fmaxf(x, __shfl_xor(x, 2, 64));
  x = fmaxf(x, __shfl_xor(x, 4, 64));
  x = fmaxf(x, __shfl_xor(x, 8, 64));
  return x;
}
__device__ __forceinline__ float red64_sum(float x){
  x += __shfl_xor(x, 1, 64);
  x += __shfl_xor(x, 2, 64);
  x += __shfl_xor(x, 4, 64);
  x += __shfl_xor(x, 8, 64);
  x += __shfl_xor(x, 16, 64);
  x += __shfl_xor(x, 32, 64);
  return x;
}

// ---------------- utility kernels ----------------

__global__ void k_zero16(u16* __restrict__ p, long n){
  long i = (long)blockIdx.x * blockDim.x + threadIdx.x;
  if (i < n) p[i] = 0;
}

__global__ void k_cast(const float* __restrict__ in, u16* __restrict__ out, long n){
  long i = ((long)blockIdx.x * blockDim.x + threadIdx.x) * 4;
  long stride = (long)gridDim.x * blockDim.x * 4;
  for (; i < n; i += stride){
    float4 f = *(const float4*)(in + i);
    bf16x4 v = { (short)f2bf(f.x), (short)f2bf(f.y), (short)f2bf(f.z), (short)f2bf(f.w) };
    *(bf16x4*)(out + i) = v;
  }
}

struct WT { const float* s; u16* d; int K; };
struct WT10 { WT w[10]; };

// in: [K][1536] fp32 -> out: [1536][K] bf16
__global__ __launch_bounds__(256) void k_transpose_w(WT10 ws){
  const WT t = ws.w[blockIdx.z];
  const int r0 = blockIdx.y * 32;
  if (r0 >= t.K) return;
  const int c0 = blockIdx.x * 32;
  __shared__ float tile[32][33];
  const int x = threadIdx.x, y = threadIdx.y;
  #pragma unroll
  for (int k = 0; k < 4; ++k)
    tile[y + 8*k][x] = t.s[(size_t)(r0 + y + 8*k) * 1536 + c0 + x];
  __syncthreads();
  #pragma unroll
  for (int k = 0; k < 4; ++k)
    t.d[(size_t)(c0 + y + 8*k) * t.K + r0 + x] = f2bf(tile[x][y + 8*k]);
}

// in: [R][C] bf16 -> out: [C][R] bf16
__global__ __launch_bounds__(256) void k_transpose_bf(const u16* __restrict__ in,
                                                      u16* __restrict__ out, int R, int C){
  const int r0 = blockIdx.y * 32, c0 = blockIdx.x * 32;
  __shared__ u16 tile[32][34];
  const int x = threadIdx.x, y = threadIdx.y;
  #pragma unroll
  for (int k = 0; k < 4; ++k)
    tile[y + 8*k][x] = in[(size_t)(r0 + y + 8*k) * C + c0 + x];
  __syncthreads();
  #pragma unroll
  for (int k = 0; k < 4; ++k)
    out[(size_t)(c0 + y + 8*k) * R + r0 + x] = tile[x][y + 8*k];
}

// ---------------- GEMM: C[M][N] = A[M][K](bf16) * BT[N][K](bf16)^T + bias ----------------

#define LDT 72

template<int OUTF32>
__global__ __launch_bounds__(256) void k_gemm_bt(
  const u16* __restrict__ A, int lda,
  const u16* __restrict__ BT, int ldb,
  void* __restrict__ Cv, int ldc,
  const float* __restrict__ bias,
  int M, int N, int K)
{
  __shared__ u16 As[128 * LDT];
  __shared__ u16 Bs[128 * LDT];
  const int tid = threadIdx.x;
  const int lane = tid & 63, wid = tid >> 6;
  const int l15 = lane & 15, l4 = lane >> 4;
  const int m0 = blockIdx.y * 128, n0 = blockIdx.x * 128;
  const int wm = (wid >> 1) * 64, wn = (wid & 1) * 64;
  const int srow = tid >> 1, scol = (tid & 1) * 32;

  f32x4 acc[4][4];
  #pragma unroll
  for (int i = 0; i < 4; ++i)
    #pragma unroll
    for (int j = 0; j < 4; ++j)
      acc[i][j] = (f32x4){0.f, 0.f, 0.f, 0.f};

  const bool aval = (m0 + srow) < M;
  const bool bval = (n0 + srow) < N;
  const u16* aptr = A + (size_t)(m0 + srow) * lda + scol;
  const u16* bptr = BT + (size_t)(n0 + srow) * ldb + scol;
  u16* asdst = &As[srow * LDT + scol];
  u16* bsdst = &Bs[srow * LDT + scol];
  const bf16x8 zz = {0,0,0,0,0,0,0,0};

  for (int k0 = 0; k0 < K; k0 += 64){
    #pragma unroll
    for (int i = 0; i < 4; ++i){
      bf16x8 av = aval ? *(const bf16x8*)(aptr + k0 + 8*i) : zz;
      *(bf16x8*)(asdst + 8*i) = av;
      bf16x8 bv = bval ? *(const bf16x8*)(bptr + k0 + 8*i) : zz;
      *(bf16x8*)(bsdst + 8*i) = bv;
    }
    __syncthreads();
    #pragma unroll
    for (int kk = 0; kk < 2; ++kk){
      const int ko = kk * 32 + 4 * l4;
      bf16x8 a[4], b[4];
      #pragma unroll
      for (int m = 0; m < 4; ++m) a[m] = ldfrag(&As[(wm + m*16 + l15) * LDT + ko]);
      #pragma unroll
      for (int n = 0; n < 4; ++n) b[n] = ldfrag(&Bs[(wn + n*16 + l15) * LDT + ko]);
      #pragma unroll
      for (int m = 0; m < 4; ++m)
        #pragma unroll
        for (int n = 0; n < 4; ++n)
          acc[m][n] = MFMA(a[m], b[n], acc[m][n]);
    }
    __syncthreads();
  }

  #pragma unroll
  for (int n = 0; n < 4; ++n){
    const int col = n0 + wn + n*16 + l15;
    const float bi = bias ? bias[col] : 0.f;
    #pragma unroll
    for (int m = 0; m < 4; ++m){
      const int row0 = m0 + wm + m*16 + l4*4;
      #pragma unroll
      for (int r = 0; r < 4; ++r){
        const int row = row0 + r;
        if (row < M){
          float val = acc[m][n][r] + bi;
          if (OUTF32) ((float*)Cv)[(size_t)row * ldc + col] = val;
          else        ((u16*)Cv)[(size_t)row * ldc + col] = f2bf(val);
        }
      }
    }
  }
}

// ---------------- cross attention (gated, NP=256 keys) ----------------

__global__ __launch_bounds__(256) void k_cross_attn(
  const u16* __restrict__ Q,     // [*, 1536], rows 0..2047 used
  const u16* __restrict__ Kp,    // [256][1536]
  const u16* __restrict__ VpT,   // [1536][256]
  const float* __restrict__ clip,
  const float* __restrict__ Wsl, // [512]
  const float* __restrict__ bslp,
  float* __restrict__ multi)     // [2048][1536]
{
  const int h = blockIdx.y;
  const int tid = threadIdx.x, lane = tid & 63, wid = tid >> 6;
  const int l15 = lane & 15, l4 = lane >> 4;
  const int qbase = blockIdx.x * 128 + wid * 32;
  __shared__ u16 Pl[4][16 * 264];
  u16* myP = Pl[wid];

  float cd = 0.f;
  for (int p = lane; p < 256; p += 64) cd += clip[p] * Wsl[256 + p];
  cd = red64_sum(cd);
  const float gate_c = cd + bslp[0];

  bf16x8 qf[2][2];
  #pragma unroll
  for (int rb = 0; rb < 2; ++rb)
    #pragma unroll
    for (int kk = 0; kk < 2; ++kk)
      qf[rb][kk] = ldfrag(Q + (size_t)(qbase + rb*16 + l15) * 1536 + h*64 + kk*32 + 4*l4);

  // pass 1: weighted row-sums for the gate
  float gs[2][4] = {};
  for (int n = 0; n < 16; ++n){
    const int key = n * 16 + l15;
    const u16* kb = Kp + (size_t)key * 1536 + h * 64 + 4 * l4;
    bf16x8 kf0 = ldfrag(kb);
    bf16x8 kf1 = ldfrag(kb + 32);
    const float w = Wsl[key];
    #pragma unroll
    for (int rb = 0; rb < 2; ++rb){
      f32x4 t = {0.f, 0.f, 0.f, 0.f};
      t = MFMA(qf[rb][0], kf0, t);
      t = MFMA(qf[rb][1], kf1, t);
      #pragma unroll
      for (int r = 0; r < 4; ++r) gs[rb][r] += t[r] * w;
    }
  }
  float gate[2][4];
  #pragma unroll
  for (int rb = 0; rb < 2; ++rb)
    #pragma unroll
    for (int r = 0; r < 4; ++r)
      gate[rb][r] = red16_sum(gs[rb][r]) * SCALE + gate_c;

  f32x4 O[2][4];
  #pragma unroll
  for (int rb = 0; rb < 2; ++rb)
    #pragma unroll
    for (int nb = 0; nb < 4; ++nb)
      O[rb][nb] = (f32x4){0.f, 0.f, 0.f, 0.f};
  float linv[2][4];

  #pragma unroll
  for (int rb = 0; rb < 2; ++rb){
    f32x4 s[16];
    #pragma unroll
    for (int n = 0; n < 16; ++n){
      const int key = n * 16 + l15;
      const u16* kb = Kp + (size_t)key * 1536 + h * 64 + 4 * l4;
      f32x4 t = {0.f, 0.f, 0.f, 0.f};
      t = MFMA(qf[rb][0], ldfrag(kb), t);
      t = MFMA(qf[rb][1], ldfrag(kb + 32), t);
      const float cl = clip[key];
      #pragma unroll
      for (int r = 0; r < 4; ++r) s[n][r] = t[r] * SCALE + gate[rb][r] * cl;
    }
    float mx[4] = {-1e30f, -1e30f, -1e30f, -1e30f};
    #pragma unroll
    for (int n = 0; n < 16; ++n)
      #pragma unroll
      for (int r = 0; r < 4; ++r) mx[r] = fmaxf(mx[r], s[n][r]);
    #pragma unroll
    for (int r = 0; r < 4; ++r) mx[r] = red16_max(mx[r]);
    float ls[4] = {};
    #pragma unroll
    for (int n = 0; n < 16; ++n)
      #pragma unroll
      for (int r = 0; r < 4; ++r){
        float p = __expf(s[n][r] - mx[r]);
        s[n][r] = p; ls[r] += p;
      }
    #pragma unroll
    for (int r = 0; r < 4; ++r){ ls[r] = red16_sum(ls[r]); linv[rb][r] = 1.f / ls[r]; }

    #pragma unroll
    for (int n = 0; n < 16; ++n)
      #pragma unroll
      for (int r = 0; r < 4; ++r)
        myP[(l4*4 + r) * 264 + n*16 + l15] = f2bf(s[n][r]);
    asm volatile("s_waitcnt lgkmcnt(0)" ::: "memory");

    #pragma unroll
    for (int kk2 = 0; kk2 < 8; ++kk2){
      bf16x8 pa = ldfrag(myP + l15 * 264 + kk2*32 + 4*l4);
      #pragma unroll
      for (int nb = 0; nb < 4; ++nb){
        bf16x8 vt = ldfrag(VpT + (size_t)(h*64 + nb*16 + l15) * 256 + kk2*32 + 4*l4);
        O[rb][nb] = MFMA(pa, vt, O[rb][nb]);
      }
    }
  }

  #pragma unroll
  for (int rb = 0; rb < 2; ++rb)
    #pragma unroll
    for (int nb = 0; nb < 4; ++nb){
      const int col = h*64 + nb*16 + l15;
      #pragma unroll
      for (int r = 0; r < 4; ++r){
        const int row = qbase + rb*16 + l4*4 + r;
        multi[(size_t)row * 1536 + col] = O[rb][nb][r] * linv[rb][r];
      }
    }
}

// ---------------- self attention (flash, NTOT=2202) ----------------

__global__ __launch_bounds__(256) void k_self_attn(
  const u16* __restrict__ q2,   // [2304][1536]
  const u16* __restrict__ k2,   // [2304][1536]
  const u16* __restrict__ v2T,  // [1536][2304]
  float* __restrict__ hsout)    // [2202][1536]
{
  const int h = blockIdx.y;
  const int tid = threadIdx.x, lane = tid & 63, wid = tid >> 6;
  const int l15 = lane & 15, l4 = lane >> 4;
  const int qbase = blockIdx.x * 128 + wid * 32;
  __shared__ u16 Pl[4][16 * 72];
  u16* myP = Pl[wid];

  bf16x8 qf[2][2];
  #pragma unroll
  for (int rb = 0; rb < 2; ++rb)
    #pragma unroll
    for (int kk = 0; kk < 2; ++kk)
      qf[rb][kk] = ldfrag(q2 + (size_t)(qbase + rb*16 + l15) * 1536 + h*64 + kk*32 + 4*l4);

  f32x4 O[2][4];
  float m_[2][4], l_[2][4];
  #pragma unroll
  for (int rb = 0; rb < 2; ++rb){
    #pragma unroll
    for (int nb = 0; nb < 4; ++nb) O[rb][nb] = (f32x4){0.f, 0.f, 0.f, 0.f};
    #pragma unroll
    for (int r = 0; r < 4; ++r){ m_[rb][r] = -1e30f; l_[rb][r] = 0.f; }
  }

  for (int nt = 0; nt < 35; ++nt){
    const int kt0 = nt * 64;
    #pragma unroll
    for (int rb = 0; rb < 2; ++rb){
      f32x4 s[4];
      #pragma unroll
      for (int n4 = 0; n4 < 4; ++n4){
        const int key = kt0 + n4*16 + l15;
        const u16* kb = k2 + (size_t)key * 1536 + h*64 + 4*l4;
        f32x4 t = {0.f, 0.f, 0.f, 0.f};
        t = MFMA(qf[rb][0], ldfrag(kb), t);
        t = MFMA(qf[rb][1], ldfrag(kb + 32), t);
        const bool valid = key < NTOT;
        #pragma unroll
        for (int r = 0; r < 4; ++r) s[n4][r] = valid ? t[r] * SCALE : -1e30f;
      }
      float mt[4];
      #pragma unroll
      for (int r = 0; r < 4; ++r){
        mt[r] = fmaxf(fmaxf(s[0][r], s[1][r]), fmaxf(s[2][r], s[3][r]));
        mt[r] = red16_max(mt[r]);
      }
      float al[4], ls[4] = {};
      #pragma unroll
      for (int r = 0; r < 4; ++r){
        float mn = fmaxf(m_[rb][r], mt[r]);
        al[r] = __expf(m_[rb][r] - mn);
        m_[rb][r] = mn;
      }
      #pragma unroll
      for (int n4 = 0; n4 < 4; ++n4)
        #pragma unroll
        for (int r = 0; r < 4; ++r){
          float p = __expf(s[n4][r] - m_[rb][r]);
          s[n4][r] = p; ls[r] += p;
        }
      #pragma unroll
      for (int r = 0; r < 4; ++r){
        ls[r] = red16_sum(ls[r]);
        l_[rb][r] = l_[rb][r] * al[r] + ls[r];
      }
      #pragma unroll
      for (int nb = 0; nb < 4; ++nb)
        #pragma unroll
        for (int r = 0; r < 4; ++r) O[rb][nb][r] *= al[r];

      #pragma unroll
      for (int n4 = 0; n4 < 4; ++n4)
        #pragma unroll
        for (int r = 0; r < 4; ++r)
          myP[(l4*4 + r) * 72 + n4*16 + l15] = f2bf(s[n4][r]);
      asm volatile("s_waitcnt lgkmcnt(0)" ::: "memory");

      #pragma unroll
      for (int kk2 = 0; kk2 < 2; ++kk2){
        bf16x8 pa = ldfrag(myP + l15 * 72 + kk2*32 + 4*l4);
        #pragma unroll
        for (int nb = 0; nb < 4; ++nb){
          bf16x8 vt = ldfrag(v2T + (size_t)(h*64 + nb*16 + l15) * NPAD + kt0 + kk2*32 + 4*l4);
          O[rb][nb] = MFMA(pa, vt, O[rb][nb]);
        }
      }
    }
  }

  #pragma unroll
  for (int rb = 0; rb < 2; ++rb)
    #pragma unroll
    for (int nb = 0; nb < 4; ++nb){
      const int col = h*64 + nb*16 + l15;
      #pragma unroll
      for (int r = 0; r < 4; ++r){
        const int row = qbase + rb*16 + l4*4 + r;
        if (row < NTOT)
          hsout[(size_t)row * 1536 + col] = O[rb][nb][r] / l_[rb][r];
      }
    }
}

// ---------------- adaptive gate + blend ----------------

__global__ __launch_bounds__(256) void k_adaptive(
  const float* __restrict__ multi, const float* __restrict__ hsbuf,
  const float* __restrict__ Wad, const float* __restrict__ badp,
  u16* __restrict__ blended)
{
  const int lane = threadIdx.x & 63, wid = threadIdx.x >> 6;
  const int q = blockIdx.x * 4 + wid;
  const float* mrow = multi + (size_t)q * 1536;
  const float* hrow = hsbuf + (size_t)q * 1536;
  float acc = 0.f;
  #pragma unroll
  for (int i = 0; i < 24; ++i){
    int d = lane + 64 * i;
    acc += mrow[d] * Wad[d] + hrow[d] * Wad[1536 + d];
  }
  acc = red64_sum(acc) + badp[0];
  const float sig = 1.f / (1.f + __expf(-acc));
  const float f = BLENDF * sig;
  u16* brow = blended + (size_t)q * 1536;
  #pragma unroll
  for (int i = 0; i < 24; ++i){
    int d = lane + 64 * i;
    brow[d] = f2bf(f * mrow[d] + hrow[d]);
  }
}

// ---------------- launch ----------------

extern "C" void kernel_launch(void* const* d_in, const int* in_sizes, int n_in,
                              void* d_out, int out_size, void* d_ws, size_t ws_size,
                              hipStream_t stream)
{
  (void)in_sizes; (void)n_in; (void)out_size; (void)ws_size;
  const float* hs   = (const float*)d_in[0];
  const float* enc  = (const float*)d_in[1];
  const float* pics = (const float*)d_in[2];
  const float* clip = (const float*)d_in[3];
  const float* Wq   = (const float*)d_in[4];  const float* bq   = (const float*)d_in[5];
  const float* Wk   = (const float*)d_in[6];  const float* bk   = (const float*)d_in[7];
  const float* Wv   = (const float*)d_in[8];  const float* bv   = (const float*)d_in[9];
  const float* Waq  = (const float*)d_in[10]; const float* baq  = (const float*)d_in[11];
  const float* Wak  = (const float*)d_in[12]; const float* bak  = (const float*)d_in[13];
  const float* Wav  = (const float*)d_in[14]; const float* bav  = (const float*)d_in[15];
  const float* Wkl  = (const float*)d_in[16]; const float* Wvl  = (const float*)d_in[17];
  const float* Wsl  = (const float*)d_in[18]; const float* bsl  = (const float*)d_in[19];
  const float* Wad  = (const float*)d_in[20]; const float* bad  = (const float*)d_in[21];
  const float* Wout = (const float*)d_in[22]; const float* bout = (const float*)d_in[23];
  const float* Wadd = (const float*)d_in[24]; const float* badd = (const float*)d_in[25];

  char* ws = (char*)d_ws;
  size_t off = 0;
  auto alloc = [&](size_t b){ void* p = ws + off; off += (b + 255) & ~(size_t)255; return p; };

  u16* hs_bf  = (u16*)alloc((size_t)2048*1536*2);
  u16* enc_bf = (u16*)alloc((size_t)154*1536*2);
  u16* pics_bf= (u16*)alloc((size_t)256*1024*2);
  u16* WqT  = (u16*)alloc((size_t)1536*1536*2);
  u16* WkT  = (u16*)alloc((size_t)1536*1536*2);
  u16* WvT  = (u16*)alloc((size_t)1536*1536*2);
  u16* WaqT = (u16*)alloc((size_t)1536*1536*2);
  u16* WakT = (u16*)alloc((size_t)1536*1536*2);
  u16* WavT = (u16*)alloc((size_t)1536*1536*2);
  u16* WoutT= (u16*)alloc((size_t)1536*1536*2);
  u16* WaddT= (u16*)alloc((size_t)1536*1536*2);
  u16* WklT = (u16*)alloc((size_t)1536*1024*2);
  u16* WvlT = (u16*)alloc((size_t)1536*1024*2);
  u16* q2   = (u16*)alloc((size_t)NPAD*1536*2);
  u16* k2   = (u16*)alloc((size_t)NPAD*1536*2);
  u16* v2   = (u16*)alloc((size_t)NPAD*1536*2);
  u16* v2T  = (u16*)alloc((size_t)1536*NPAD*2);
  u16* Kp   = (u16*)alloc((size_t)256*1536*2);
  u16* Vp   = (u16*)alloc((size_t)256*1536*2);
  u16* VpT  = (u16*)alloc((size_t)1536*256*2);
  float* multi  = (float*)alloc((size_t)2048*1536*4);
  float* hsbuf  = (float*)alloc((size_t)NTOT*1536*4);
  u16* blended  = (u16*)alloc((size_t)2048*1536*2);
  u16* hstxt    = (u16*)alloc((size_t)154*1536*2);

  const long padn = (long)(NPAD - NTOT) * 1536;
  k_zero16<<<dim3((padn + 255) / 256), 256, 0, stream>>>(q2 + (size_t)NTOT*1536, padn);
  k_zero16<<<dim3((padn + 255) / 256), 256, 0, stream>>>(k2 + (size_t)NTOT*1536, padn);
  k_zero16<<<dim3((padn + 255) / 256), 256, 0, stream>>>(v2 + (size_t)NTOT*1536, padn);

  k_cast<<<dim3(3072), 256, 0, stream>>>(hs,   hs_bf,  (long)2048*1536);
  k_cast<<<dim3(231),  256, 0, stream>>>(enc,  enc_bf, (long)154*1536);
  k_cast<<<dim3(256),  256, 0, stream>>>(pics, pics_bf,(long)256*1024);

  WT10 wts;
  wts.w[0] = {Wq,   WqT,   1536};
  wts.w[1] = {Wk,   WkT,   1536};
  wts.w[2] = {Wv,   WvT,   1536};
  wts.w[3] = {Waq,  WaqT,  1536};
  wts.w[4] = {Wak,  WakT,  1536};
  wts.w[5] = {Wav,  WavT,  1536};
  wts.w[6] = {Wout, WoutT, 1536};
  wts.w[7] = {Wadd, WaddT, 1536};
  wts.w[8] = {Wkl,  WklT,  1024};
  wts.w[9] = {Wvl,  WvlT,  1024};
  k_transpose_w<<<dim3(48, 48, 10), dim3(32, 8), 0, stream>>>(wts);

  dim3 gBig(12, 16), gSm(12, 2);
  k_gemm_bt<0><<<gBig, 256, 0, stream>>>(hs_bf, 1536, WqT, 1536, (void*)q2, 1536, bq, 2048, 1536, 1536);
  k_gemm_bt<0><<<gBig, 256, 0, stream>>>(hs_bf, 1536, WkT, 1536, (void*)k2, 1536, bk, 2048, 1536, 1536);
  k_gemm_bt<0><<<gBig, 256, 0, stream>>>(hs_bf, 1536, WvT, 1536, (void*)v2, 1536, bv, 2048, 1536, 1536);
  k_gemm_bt<0><<<gSm, 256, 0, stream>>>(enc_bf, 1536, WaqT, 1536, (void*)(q2 + (size_t)2048*1536), 1536, baq, 154, 1536, 1536);
  k_gemm_bt<0><<<gSm, 256, 0, stream>>>(enc_bf, 1536, WakT, 1536, (void*)(k2 + (size_t)2048*1536), 1536, bak, 154, 1536, 1536);
  k_gemm_bt<0><<<gSm, 256, 0, stream>>>(enc_bf, 1536, WavT, 1536, (void*)(v2 + (size_t)2048*1536), 1536, bav, 154, 1536, 1536);
  k_gemm_bt<0><<<gSm, 256, 0, stream>>>(pics_bf, 1024, WklT, 1024, (void*)Kp, 1536, (const float*)nullptr, 256, 1536, 1024);
  k_gemm_bt<0><<<gSm, 256, 0, stream>>>(pics_bf, 1024, WvlT, 1024, (void*)Vp, 1536, (const float*)nullptr, 256, 1536, 1024);

  k_transpose_bf<<<dim3(48, NPAD/32), dim3(32, 8), 0, stream>>>(v2, v2T, NPAD, 1536);
  k_transpose_bf<<<dim3(48, 8),       dim3(32, 8), 0, stream>>>(Vp, VpT, 256, 1536);

  k_cross_attn<<<dim3(16, 24), 256, 0, stream>>>(q2, Kp, VpT, clip, Wsl, bsl, multi);
  k_self_attn<<<dim3(18, 24), 256, 0, stream>>>(q2, k2, v2T, hsbuf);

  k_adaptive<<<dim3(512), 256, 0, stream>>>(multi, hsbuf, Wad, bad, blended);
  k_cast<<<dim3(231), 256, 0, stream>>>(hsbuf + (size_t)2048*1536, hstxt, (long)154*1536);

  k_gemm_bt<1><<<gBig, 256, 0, stream>>>(blended, 1536, WoutT, 1536, d_out, 1536, bout, 2048, 1536, 1536);
  k_gemm_bt<1><<<gSm, 256, 0, stream>>>(hstxt, 1536, WaddT, 1536, (void*)((float*)d_out + (size_t)2048*1536), 1536, badd, 154, 1536, 1536);
}

// Round 2
// 418.340 us; speedup vs baseline: 2.8063x; 2.8063x over previous
//
#include <hip/hip_runtime.h>

typedef unsigned short u16;
typedef unsigned int u32;
typedef __attribute__((ext_vector_type(4))) short bf16x4;
typedef __attribute__((ext_vector_type(8))) short bf16x8;
typedef __attribute__((ext_vector_type(4))) float f32x4;

#define SCALE 0.125f
#define BLENDF 0.4875f
#define NTOT 2202
#define NPAD 2304

__device__ __forceinline__ u16 f2bf(float x){
  union { float f; unsigned u; } v; v.f = x;
  unsigned r = v.u + 0x7fffu + ((v.u >> 16) & 1u);
  return (u16)(r >> 16);
}

__device__ __forceinline__ f32x4 MFMA(bf16x8 a, bf16x8 b, f32x4 c){
  return __builtin_amdgcn_mfma_f32_16x16x32_bf16(a, b, c, 0, 0, 0);
}

// async global->LDS, 16B per lane; LDS dest must be wave-uniform base (+lane*16 implicit)
__device__ __forceinline__ void gload16(const u16* g, u16* l){
  __builtin_amdgcn_global_load_lds(
    (const __attribute__((address_space(1))) u32*)g,
    (__attribute__((address_space(3))) u32*)l, 16, 0, 0);
}

__device__ __forceinline__ float red16_sum(float x){
  x += __shfl_xor(x, 1, 64);
  x += __shfl_xor(x, 2, 64);
  x += __shfl_xor(x, 4, 64);
  x += __shfl_xor(x, 8, 64);
  return x;
}
__device__ __forceinline__ float red16_max(float x){
  x = fmaxf(x, __shfl_xor(x, 1, 64));
  x = fmaxf(x, __shfl_xor(x, 2, 64));
  x = fmaxf(x, __shfl_xor(x, 4, 64));
  x = fmaxf(x, __shfl_xor(x, 8, 64));
  return x;
}
__device__ __forceinline__ float red64_sum(float x){
  x += __shfl_xor(x, 1, 64);
  x += __shfl_xor(x, 2, 64);
  x += __shfl_xor(x, 4, 64);
  x += __shfl_xor(x, 8, 64);
  x += __shfl_xor(x, 16, 64);
  x += __shfl_xor(x, 32, 64);
  return x;
}

// ---------------- utility kernels ----------------

__global__ void k_zero16(u16* __restrict__ p, long n){
  long i = (long)blockIdx.x * blockDim.x + threadIdx.x;
  if (i < n) p[i] = 0;
}

__global__ void k_cast(const float* __restrict__ in, u16* __restrict__ out, long n){
  long i = ((long)blockIdx.x * blockDim.x + threadIdx.x) * 4;
  long stride = (long)gridDim.x * blockDim.x * 4;
  for (; i < n; i += stride){
    float4 f = *(const float4*)(in + i);
    bf16x4 v = { (short)f2bf(f.x), (short)f2bf(f.y), (short)f2bf(f.z), (short)f2bf(f.w) };
    *(bf16x4*)(out + i) = v;
  }
}

struct WT { const float* s; u16* d; int K; };
struct WT10 { WT w[10]; };

// in: [K][1536] fp32 -> out: [1536][K] bf16
__global__ __launch_bounds__(256) void k_transpose_w(WT10 ws){
  const WT t = ws.w[blockIdx.z];
  const int r0 = blockIdx.y * 32;
  if (r0 >= t.K) return;
  const int c0 = blockIdx.x * 32;
  __shared__ float tile[32][33];
  const int x = threadIdx.x, y = threadIdx.y;
  #pragma unroll
  for (int k = 0; k < 4; ++k)
    tile[y + 8*k][x] = t.s[(size_t)(r0 + y + 8*k) * 1536 + c0 + x];
  __syncthreads();
  #pragma unroll
  for (int k = 0; k < 4; ++k)
    t.d[(size_t)(c0 + y + 8*k) * t.K + r0 + x] = f2bf(tile[x][y + 8*k]);
}

// in: [R][C] bf16 -> out: [C][R] bf16
__global__ __launch_bounds__(256) void k_transpose_bf(const u16* __restrict__ in,
                                                      u16* __restrict__ out, int R, int C){
  const int r0 = blockIdx.y * 32, c0 = blockIdx.x * 32;
  __shared__ u16 tile[32][34];
  const int x = threadIdx.x, y = threadIdx.y;
  #pragma unroll
  for (int k = 0; k < 4; ++k)
    tile[y + 8*k][x] = in[(size_t)(r0 + y + 8*k) * C + c0 + x];
  __syncthreads();
  #pragma unroll
  for (int k = 0; k < 4; ++k)
    out[(size_t)(c0 + y + 8*k) * R + r0 + x] = tile[x][y + 8*k];
}

// ---------------- GEMM (m97 structure): C = A[M][K] * BT[N][K]^T, fused N-segments ----------------

struct GOuts { void* C[3]; const float* b[3]; };

template<int OUTF32>
__global__ __launch_bounds__(256, 2) void k_gemm(
  const u16* __restrict__ A, int lda,
  const u16* __restrict__ BT, int ldb,
  GOuts o, int ldc, int M, int N, int K)
{
  __shared__ alignas(1024) u16 As[128 * 64];
  __shared__ alignas(1024) u16 Bs[128 * 64];
  const int tid = threadIdx.x, lane = tid & 63, w = tid >> 6;
  const int l15 = lane & 15, l4 = lane >> 4;
  const int m0 = blockIdx.y * 128, n0 = blockIdx.x * 128;
  const int wm = (w >> 1) * 64, wn = (w & 1) * 64;

  f32x4 acc[4][4];
  #pragma unroll
  for (int i = 0; i < 4; ++i)
    #pragma unroll
    for (int j = 0; j < 4; ++j)
      acc[i][j] = (f32x4){0.f, 0.f, 0.f, 0.f};

  const int srow = w * 8 + (lane >> 3);
  const int scb  = (lane & 7) * 16;

  for (int k0 = 0; k0 < K; k0 += 64){
    #pragma unroll
    for (int c = 0; c < 4; ++c){
      const int dr = c * 32 + srow;
      const int cb = scb ^ ((dr & 7) << 4);          // pre-swizzled global source (T2 both-sides)
      const int ar = min(m0 + dr, M - 1);
      gload16(A + (size_t)ar * lda + k0 + (cb >> 1), &As[c * 2048 + w * 512]);
      const int br = min(n0 + dr, N - 1);
      gload16(BT + (size_t)br * ldb + k0 + (cb >> 1), &Bs[c * 2048 + w * 512]);
    }
    asm volatile("s_waitcnt vmcnt(0)" ::: "memory");
    __syncthreads();
    #pragma unroll
    for (int kk = 0; kk < 2; ++kk){
      const int kb = (kk * 64 + l4 * 16) ^ ((l15 & 7) << 4);  // swizzled read
      bf16x8 a[4], b[4];
      #pragma unroll
      for (int m = 0; m < 4; ++m)
        a[m] = *(const bf16x8*)((const char*)As + (wm + m*16 + l15) * 128 + kb);
      #pragma unroll
      for (int n = 0; n < 4; ++n)
        b[n] = *(const bf16x8*)((const char*)Bs + (wn + n*16 + l15) * 128 + kb);
      #pragma unroll
      for (int m = 0; m < 4; ++m)
        #pragma unroll
        for (int n = 0; n < 4; ++n)
          acc[m][n] = MFMA(a[m], b[n], acc[m][n]);
    }
    __syncthreads();
  }

  #pragma unroll
  for (int n = 0; n < 4; ++n){
    const int colg = n0 + wn + n*16 + l15;
    const int sel = colg / 1536;
    const int col = colg - sel * 1536;
    const float* bp = o.b[sel];
    const float bi = bp ? bp[col] : 0.f;
    #pragma unroll
    for (int m = 0; m < 4; ++m){
      const int row0 = m0 + wm + m*16 + l4*4;
      #pragma unroll
      for (int r = 0; r < 4; ++r){
        const int row = row0 + r;
        if (row < M){
          float val = acc[m][n][r] + bi;
          if (OUTF32) ((float*)o.C[sel])[(size_t)row * ldc + col] = val;
          else        ((u16*)o.C[sel])[(size_t)row * ldc + col] = f2bf(val);
        }
      }
    }
  }
}

// ---------------- cross attention (gated, NP=256 keys), single pass ----------------

__global__ __launch_bounds__(256, 2) void k_cross_attn(
  const u16* __restrict__ Q,     // [*, 1536], rows 0..2047 used
  const u16* __restrict__ Kp,    // [256][1536]
  const u16* __restrict__ VpT,   // [1536][256]
  const float* __restrict__ clip,
  const float* __restrict__ Wsl, // [512]
  const float* __restrict__ bslp,
  float* __restrict__ multi)     // [2048][1536]
{
  const int h = blockIdx.y;
  const int tid = threadIdx.x, lane = tid & 63, wid = tid >> 6;
  const int l15 = lane & 15, l4 = lane >> 4;
  const int qbase = blockIdx.x * 128 + wid * 32;
  __shared__ alignas(16) u16 Pl[4][16 * 264];
  u16* myP = Pl[wid];

  float cd = 0.f;
  for (int p = lane; p < 256; p += 64) cd += clip[p] * Wsl[256 + p];
  cd = red64_sum(cd);
  const float gate_c = cd + bslp[0];

  bf16x8 qf[2][2];
  #pragma unroll
  for (int rb = 0; rb < 2; ++rb)
    #pragma unroll
    for (int kk = 0; kk < 2; ++kk)
      qf[rb][kk] = *(const bf16x8*)(Q + (size_t)(qbase + rb*16 + l15) * 1536 + h*64 + kk*32 + l4*8);

  f32x4 O[2][4];
  #pragma unroll
  for (int rb = 0; rb < 2; ++rb)
    #pragma unroll
    for (int nb = 0; nb < 4; ++nb)
      O[rb][nb] = (f32x4){0.f, 0.f, 0.f, 0.f};
  float linv[2][4];

  #pragma unroll
  for (int rb = 0; rb < 2; ++rb){
    f32x4 s[16];
    #pragma unroll
    for (int n = 0; n < 16; ++n){
      const int key = n * 16 + l15;
      const u16* kb = Kp + (size_t)key * 1536 + h * 64 + l4 * 8;
      f32x4 t = {0.f, 0.f, 0.f, 0.f};
      t = MFMA(qf[rb][0], *(const bf16x8*)(kb), t);
      t = MFMA(qf[rb][1], *(const bf16x8*)(kb + 32), t);
      #pragma unroll
      for (int r = 0; r < 4; ++r) s[n][r] = t[r] * SCALE;
    }
    // gate = sum_k scores*Wsl[:256] + gate_c
    float gs[4] = {};
    #pragma unroll
    for (int n = 0; n < 16; ++n){
      const float wn = Wsl[n * 16 + l15];
      #pragma unroll
      for (int r = 0; r < 4; ++r) gs[r] += s[n][r] * wn;
    }
    float gate[4];
    #pragma unroll
    for (int r = 0; r < 4; ++r) gate[r] = red16_sum(gs[r]) + gate_c;
    // s += gate * clip[key]
    #pragma unroll
    for (int n = 0; n < 16; ++n){
      const float cl = clip[n * 16 + l15];
      #pragma unroll
      for (int r = 0; r < 4; ++r) s[n][r] += gate[r] * cl;
    }
    float mx[4] = {-1e30f, -1e30f, -1e30f, -1e30f};
    #pragma unroll
    for (int n = 0; n < 16; ++n)
      #pragma unroll
      for (int r = 0; r < 4; ++r) mx[r] = fmaxf(mx[r], s[n][r]);
    #pragma unroll
    for (int r = 0; r < 4; ++r) mx[r] = red16_max(mx[r]);
    float ls[4] = {};
    #pragma unroll
    for (int n = 0; n < 16; ++n)
      #pragma unroll
      for (int r = 0; r < 4; ++r){
        float p = __expf(s[n][r] - mx[r]);
        s[n][r] = p; ls[r] += p;
      }
    #pragma unroll
    for (int r = 0; r < 4; ++r){ ls[r] = red16_sum(ls[r]); linv[rb][r] = 1.f / ls[r]; }

    #pragma unroll
    for (int n = 0; n < 16; ++n)
      #pragma unroll
      for (int r = 0; r < 4; ++r)
        myP[(l4*4 + r) * 264 + n*16 + l15] = f2bf(s[n][r]);
    asm volatile("s_waitcnt lgkmcnt(0)" ::: "memory");
    __builtin_amdgcn_sched_barrier(0);

    #pragma unroll
    for (int kk2 = 0; kk2 < 8; ++kk2){
      bf16x8 pa = *(const bf16x8*)((const char*)myP + l15 * 528 + kk2 * 64 + l4 * 16);
      #pragma unroll
      for (int nb = 0; nb < 4; ++nb){
        bf16x8 vt = *(const bf16x8*)(VpT + (size_t)(h*64 + nb*16 + l15) * 256 + kk2*32 + l4*8);
        O[rb][nb] = MFMA(pa, vt, O[rb][nb]);
      }
    }
  }

  #pragma unroll
  for (int rb = 0; rb < 2; ++rb)
    #pragma unroll
    for (int nb = 0; nb < 4; ++nb){
      const int col = h*64 + nb*16 + l15;
      #pragma unroll
      for (int r = 0; r < 4; ++r){
        const int row = qbase + rb*16 + l4*4 + r;
        multi[(size_t)row * 1536 + col] = O[rb][nb][r] * linv[rb][r];
      }
    }
}

// ---------------- self attention (flash, LDS-staged K/V^T, double-buffered) ----------------

__global__ __launch_bounds__(256, 3) void k_self_attn(
  const u16* __restrict__ q2,   // [2304][1536]
  const u16* __restrict__ k2,   // [2304][1536]
  const u16* __restrict__ v2T,  // [1536][2304]
  float* __restrict__ hsout)    // [2202][1536]
{
  const int h = blockIdx.y;
  const int tid = threadIdx.x, lane = tid & 63, w = tid >> 6;
  const int l15 = lane & 15, l4 = lane >> 4;
  const int qrow = blockIdx.x * 64 + w * 16 + l15;

  __shared__ alignas(1024) u16 Ks[2][64 * 64];
  __shared__ alignas(1024) u16 VTs[2][64 * 64];
  __shared__ alignas(16) u16 Pl[4][16 * 72];
  u16* myP = Pl[w];

  bf16x8 qf[2];
  #pragma unroll
  for (int kk = 0; kk < 2; ++kk)
    qf[kk] = *(const bf16x8*)(q2 + (size_t)qrow * 1536 + h*64 + kk*32 + l4*8);

  f32x4 O[4];
  float m_[4], l_[4];
  #pragma unroll
  for (int nb = 0; nb < 4; ++nb) O[nb] = (f32x4){0.f, 0.f, 0.f, 0.f};
  #pragma unroll
  for (int r = 0; r < 4; ++r){ m_[r] = -1e30f; l_[r] = 0.f; }

  const int srow = w * 8 + (lane >> 3);
  const int scb  = (lane & 7) * 16;

  auto STAGE = [&](int buf, int kt0){
    #pragma unroll
    for (int c = 0; c < 2; ++c){
      const int r = c * 32 + srow;
      const int cb = scb ^ ((r & 7) << 4);
      gload16(k2 + (size_t)(kt0 + r) * 1536 + h*64 + (cb >> 1), &Ks[buf][c*2048 + w*512]);
      gload16(v2T + (size_t)(h*64 + r) * NPAD + kt0 + (cb >> 1), &VTs[buf][c*2048 + w*512]);
    }
  };

  STAGE(0, 0);
  asm volatile("s_waitcnt vmcnt(0)" ::: "memory");
  __syncthreads();

  int buf = 0;
  for (int nt = 0; nt < 35; ++nt){          // tile 35 (keys 2240..2303) fully masked -> skipped
    if (nt + 1 < 35) STAGE(buf ^ 1, (nt + 1) * 64);
    const int kt0 = nt * 64;

    // QK^T
    f32x4 s[4];
    #pragma unroll
    for (int n4 = 0; n4 < 4; ++n4){
      const int key = n4 * 16 + l15;
      f32x4 t = {0.f, 0.f, 0.f, 0.f};
      #pragma unroll
      for (int kk = 0; kk < 2; ++kk){
        bf16x8 kf = *(const bf16x8*)((const char*)&Ks[buf][key * 64] +
                                     ((kk*64 + l4*16) ^ ((key & 7) << 4)));
        t = MFMA(qf[kk], kf, t);
      }
      const bool valid = (kt0 + key) < NTOT;
      #pragma unroll
      for (int r = 0; r < 4; ++r) s[n4][r] = valid ? t[r] * SCALE : -1e30f;
    }

    // online softmax
    float mt[4];
    #pragma unroll
    for (int r = 0; r < 4; ++r){
      mt[r] = fmaxf(fmaxf(s[0][r], s[1][r]), fmaxf(s[2][r], s[3][r]));
      mt[r] = red16_max(mt[r]);
    }
    float al[4], ls[4] = {};
    #pragma unroll
    for (int r = 0; r < 4; ++r){
      float mn = fmaxf(m_[r], mt[r]);
      al[r] = __expf(m_[r] - mn);
      m_[r] = mn;
    }
    #pragma unroll
    for (int n4 = 0; n4 < 4; ++n4)
      #pragma unroll
      for (int r = 0; r < 4; ++r){
        float p = __expf(s[n4][r] - m_[r]);
        s[n4][r] = p; ls[r] += p;
      }
    #pragma unroll
    for (int r = 0; r < 4; ++r){
      ls[r] = red16_sum(ls[r]);
      l_[r] = l_[r] * al[r] + ls[r];
    }
    #pragma unroll
    for (int nb = 0; nb < 4; ++nb)
      #pragma unroll
      for (int r = 0; r < 4; ++r) O[nb][r] *= al[r];

    // P -> LDS (per-wave), then PV
    #pragma unroll
    for (int n4 = 0; n4 < 4; ++n4)
      #pragma unroll
      for (int r = 0; r < 4; ++r)
        myP[(l4*4 + r) * 72 + n4*16 + l15] = f2bf(s[n4][r]);
    asm volatile("s_waitcnt lgkmcnt(0)" ::: "memory");
    __builtin_amdgcn_sched_barrier(0);

    #pragma unroll
    for (int kk = 0; kk < 2; ++kk){
      bf16x8 pa = *(const bf16x8*)((const char*)myP + l15 * 144 + kk*64 + l4*16);
      #pragma unroll
      for (int nb = 0; nb < 4; ++nb){
        const int d = nb * 16 + l15;
        bf16x8 vt = *(const bf16x8*)((const char*)&VTs[buf][d * 64] +
                                     ((kk*64 + l4*16) ^ ((d & 7) << 4)));
        O[nb] = MFMA(pa, vt, O[nb]);
      }
    }

    asm volatile("s_waitcnt vmcnt(0)" ::: "memory");
    __syncthreads();
    buf ^= 1;
  }

  #pragma unroll
  for (int r = 0; r < 4; ++r){
    const int row = blockIdx.x * 64 + w * 16 + l4*4 + r;
    if (row < NTOT){
      const float li = 1.f / l_[r];
      #pragma unroll
      for (int nb = 0; nb < 4; ++nb)
        hsout[(size_t)row * 1536 + h*64 + nb*16 + l15] = O[nb][r] * li;
    }
  }
}

// ---------------- adaptive gate + blend ----------------

__global__ __launch_bounds__(256) void k_adaptive(
  const float* __restrict__ multi, const float* __restrict__ hsbuf,
  const float* __restrict__ Wad, const float* __restrict__ badp,
  u16* __restrict__ blended)
{
  const int lane = threadIdx.x & 63, wid = threadIdx.x >> 6;
  const int q = blockIdx.x * 4 + wid;
  const float* mrow = multi + (size_t)q * 1536;
  const float* hrow = hsbuf + (size_t)q * 1536;
  float acc = 0.f;
  #pragma unroll
  for (int i = 0; i < 24; ++i){
    int d = lane + 64 * i;
    acc += mrow[d] * Wad[d] + hrow[d] * Wad[1536 + d];
  }
  acc = red64_sum(acc) + badp[0];
  const float sig = 1.f / (1.f + __expf(-acc));
  const float f = BLENDF * sig;
  u16* brow = blended + (size_t)q * 1536;
  #pragma unroll
  for (int i = 0; i < 24; ++i){
    int d = lane + 64 * i;
    brow[d] = f2bf(f * mrow[d] + hrow[d]);
  }
}

// ---------------- launch ----------------

extern "C" void kernel_launch(void* const* d_in, const int* in_sizes, int n_in,
                              void* d_out, int out_size, void* d_ws, size_t ws_size,
                              hipStream_t stream)
{
  (void)in_sizes; (void)n_in; (void)out_size; (void)ws_size;
  const float* hs   = (const float*)d_in[0];
  const float* enc  = (const float*)d_in[1];
  const float* pics = (const float*)d_in[2];
  const float* clip = (const float*)d_in[3];
  const float* Wq   = (const float*)d_in[4];  const float* bq   = (const float*)d_in[5];
  const float* Wk   = (const float*)d_in[6];  const float* bk   = (const float*)d_in[7];
  const float* Wv   = (const float*)d_in[8];  const float* bv   = (const float*)d_in[9];
  const float* Waq  = (const float*)d_in[10]; const float* baq  = (const float*)d_in[11];
  const float* Wak  = (const float*)d_in[12]; const float* bak  = (const float*)d_in[13];
  const float* Wav  = (const float*)d_in[14]; const float* bav  = (const float*)d_in[15];
  const float* Wkl  = (const float*)d_in[16]; const float* Wvl  = (const float*)d_in[17];
  const float* Wsl  = (const float*)d_in[18]; const float* bsl  = (const float*)d_in[19];
  const float* Wad  = (const float*)d_in[20]; const float* bad  = (const float*)d_in[21];
  const float* Wout = (const float*)d_in[22]; const float* bout = (const float*)d_in[23];
  const float* Wadd = (const float*)d_in[24]; const float* badd = (const float*)d_in[25];

  char* ws = (char*)d_ws;
  size_t off = 0;
  auto alloc = [&](size_t b){ void* p = ws + off; off += (b + 255) & ~(size_t)255; return p; };

  u16* hs_bf  = (u16*)alloc((size_t)2048*1536*2);
  u16* enc_bf = (u16*)alloc((size_t)154*1536*2);
  u16* pics_bf= (u16*)alloc((size_t)256*1024*2);
  // QKV weights contiguous (each 1536*1536*2 = multiple of 256)
  u16* WqT  = (u16*)alloc((size_t)1536*1536*2);
  u16* WkT  = (u16*)alloc((size_t)1536*1536*2);
  u16* WvT  = (u16*)alloc((size_t)1536*1536*2);
  u16* WaqT = (u16*)alloc((size_t)1536*1536*2);
  u16* WakT = (u16*)alloc((size_t)1536*1536*2);
  u16* WavT = (u16*)alloc((size_t)1536*1536*2);
  u16* WoutT= (u16*)alloc((size_t)1536*1536*2);
  u16* WaddT= (u16*)alloc((size_t)1536*1536*2);
  u16* WklT = (u16*)alloc((size_t)1536*1024*2);
  u16* WvlT = (u16*)alloc((size_t)1536*1024*2);
  u16* q2   = (u16*)alloc((size_t)NPAD*1536*2);
  u16* k2   = (u16*)alloc((size_t)NPAD*1536*2);
  u16* v2   = (u16*)alloc((size_t)NPAD*1536*2);
  u16* v2T  = (u16*)alloc((size_t)1536*NPAD*2);
  u16* Kp   = (u16*)alloc((size_t)256*1536*2);
  u16* Vp   = (u16*)alloc((size_t)256*1536*2);
  u16* VpT  = (u16*)alloc((size_t)1536*256*2);
  float* multi  = (float*)alloc((size_t)2048*1536*4);
  float* hsbuf  = (float*)alloc((size_t)NTOT*1536*4);
  u16* blended  = (u16*)alloc((size_t)2048*1536*2);
  u16* hstxt    = (u16*)alloc((size_t)154*1536*2);

  const long padn = (long)(NPAD - NTOT) * 1536;
  k_zero16<<<dim3((padn + 255) / 256), 256, 0, stream>>>(q2 + (size_t)NTOT*1536, padn);
  k_zero16<<<dim3((padn + 255) / 256), 256, 0, stream>>>(k2 + (size_t)NTOT*1536, padn);
  k_zero16<<<dim3((padn + 255) / 256), 256, 0, stream>>>(v2 + (size_t)NTOT*1536, padn);

  k_cast<<<dim3(3072), 256, 0, stream>>>(hs,   hs_bf,  (long)2048*1536);
  k_cast<<<dim3(231),  256, 0, stream>>>(enc,  enc_bf, (long)154*1536);
  k_cast<<<dim3(256),  256, 0, stream>>>(pics, pics_bf,(long)256*1024);

  WT10 wts;
  wts.w[0] = {Wq,   WqT,   1536};
  wts.w[1] = {Wk,   WkT,   1536};
  wts.w[2] = {Wv,   WvT,   1536};
  wts.w[3] = {Waq,  WaqT,  1536};
  wts.w[4] = {Wak,  WakT,  1536};
  wts.w[5] = {Wav,  WavT,  1536};
  wts.w[6] = {Wout, WoutT, 1536};
  wts.w[7] = {Wadd, WaddT, 1536};
  wts.w[8] = {Wkl,  WklT,  1024};
  wts.w[9] = {Wvl,  WvlT,  1024};
  k_transpose_w<<<dim3(48, 48, 10), dim3(32, 8), 0, stream>>>(wts);

  // fused QKV: N = 3*1536, B weights contiguous starting at WqT
  GOuts oqkv; oqkv.C[0] = q2; oqkv.C[1] = k2; oqkv.C[2] = v2;
  oqkv.b[0] = bq; oqkv.b[1] = bk; oqkv.b[2] = bv;
  k_gemm<0><<<dim3(36, 16), 256, 0, stream>>>(hs_bf, 1536, WqT, 1536, oqkv, 1536, 2048, 4608, 1536);

  GOuts oenc; oenc.C[0] = q2 + (size_t)2048*1536; oenc.C[1] = k2 + (size_t)2048*1536; oenc.C[2] = v2 + (size_t)2048*1536;
  oenc.b[0] = baq; oenc.b[1] = bak; oenc.b[2] = bav;
  k_gemm<0><<<dim3(36, 2), 256, 0, stream>>>(enc_bf, 1536, WaqT, 1536, oenc, 1536, 154, 4608, 1536);

  GOuts okv; okv.C[0] = Kp; okv.C[1] = Vp; okv.C[2] = nullptr;
  okv.b[0] = nullptr; okv.b[1] = nullptr; okv.b[2] = nullptr;
  k_gemm<0><<<dim3(24, 2), 256, 0, stream>>>(pics_bf, 1024, WklT, 1024, okv, 1536, 256, 3072, 1024);

  k_transpose_bf<<<dim3(48, NPAD/32), dim3(32, 8), 0, stream>>>(v2, v2T, NPAD, 1536);
  k_transpose_bf<<<dim3(48, 8),       dim3(32, 8), 0, stream>>>(Vp, VpT, 256, 1536);

  k_cross_attn<<<dim3(16, 24), 256, 0, stream>>>(q2, Kp, VpT, clip, Wsl, bsl, multi);
  k_self_attn<<<dim3(36, 24), 256, 0, stream>>>(q2, k2, v2T, hsbuf);

  k_adaptive<<<dim3(512), 256, 0, stream>>>(multi, hsbuf, Wad, bad, blended);
  k_cast<<<dim3(231), 256, 0, stream>>>(hsbuf + (size_t)2048*1536, hstxt, (long)154*1536);

  GOuts oout; oout.C[0] = d_out; oout.C[1] = nullptr; oout.C[2] = nullptr;
  oout.b[0] = bout; oout.b[1] = nullptr; oout.b[2] = nullptr;
  k_gemm<1><<<dim3(12, 16), 256, 0, stream>>>(blended, 1536, WoutT, 1536, oout, 1536, 2048, 1536, 1536);

  GOuts oadd; oadd.C[0] = (float*)d_out + (size_t)2048*1536; oadd.C[1] = nullptr; oadd.C[2] = nullptr;
  oadd.b[0] = badd; oadd.b[1] = nullptr; oadd.b[2] = nullptr;
  k_gemm<1><<<dim3(12, 2), 256, 0, stream>>>(hstxt, 1536, WaddT, 1536, oadd, 1536, 154, 1536, 1536);
}

// Round 3
// 400.757 us; speedup vs baseline: 2.9294x; 1.0439x over previous
//
#include <hip/hip_runtime.h>

typedef unsigned short u16;
typedef unsigned int u32;
typedef __attribute__((ext_vector_type(4))) short bf16x4;
typedef __attribute__((ext_vector_type(8))) short bf16x8;
typedef __attribute__((ext_vector_type(4))) float f32x4;

#define SCALE 0.125f
#define BLENDF 0.4875f
#define NTOT 2202
#define NPAD 2304
#define L2E 1.44269504f

__device__ __forceinline__ u16 f2bf(float x){
  union { float f; unsigned u; } v; v.f = x;
  unsigned r = v.u + 0x7fffu + ((v.u >> 16) & 1u);
  return (u16)(r >> 16);
}

__device__ __forceinline__ float fexp2(float x){
#if __has_builtin(__builtin_amdgcn_exp2f)
  return __builtin_amdgcn_exp2f(x);
#else
  return __expf(x * 0.6931472f);
#endif
}

__device__ __forceinline__ f32x4 MFMA(bf16x8 a, bf16x8 b, f32x4 c){
  return __builtin_amdgcn_mfma_f32_16x16x32_bf16(a, b, c, 0, 0, 0);
}

// async global->LDS, 16B per lane; LDS dest is wave-uniform base (+lane*16 implicit)
__device__ __forceinline__ void gload16(const u16* g, u16* l){
  __builtin_amdgcn_global_load_lds(
    (const __attribute__((address_space(1))) u32*)g,
    (__attribute__((address_space(3))) u32*)l, 16, 0, 0);
}

__device__ __forceinline__ float red64_sum(float x){
  x += __shfl_xor(x, 1, 64);
  x += __shfl_xor(x, 2, 64);
  x += __shfl_xor(x, 4, 64);
  x += __shfl_xor(x, 8, 64);
  x += __shfl_xor(x, 16, 64);
  x += __shfl_xor(x, 32, 64);
  return x;
}
// reduce over the l4 axis (lanes sharing the same lane&15)
__device__ __forceinline__ float redl4_sum(float x){
  x += __shfl_xor(x, 16, 64);
  x += __shfl_xor(x, 32, 64);
  return x;
}
__device__ __forceinline__ float redl4_max(float x){
  x = fmaxf(x, __shfl_xor(x, 16, 64));
  x = fmaxf(x, __shfl_xor(x, 32, 64));
  return x;
}

// ---------------- utility kernels ----------------

__global__ void k_zeropad(u16* __restrict__ a, u16* __restrict__ b,
                          u16* __restrict__ c, long n8){
  long i = (long)blockIdx.x * blockDim.x + threadIdx.x;
  if (i < n8){
    const bf16x8 z = {0,0,0,0,0,0,0,0};
    *(bf16x8*)(a + i*8) = z;
    *(bf16x8*)(b + i*8) = z;
    *(bf16x8*)(c + i*8) = z;
  }
}

__global__ void k_cast(const float* __restrict__ in, u16* __restrict__ out, long n){
  long i = ((long)blockIdx.x * blockDim.x + threadIdx.x) * 4;
  long stride = (long)gridDim.x * blockDim.x * 4;
  for (; i < n; i += stride){
    float4 f = *(const float4*)(in + i);
    bf16x4 v = { (short)f2bf(f.x), (short)f2bf(f.y), (short)f2bf(f.z), (short)f2bf(f.w) };
    *(bf16x4*)(out + i) = v;
  }
}

struct WT { const float* s; u16* d; int K; };
struct WT10 { WT w[10]; };

// in: [K][1536] fp32 -> out: [1536][K] bf16
__global__ __launch_bounds__(256) void k_transpose_w(WT10 ws){
  const WT t = ws.w[blockIdx.z];
  const int r0 = blockIdx.y * 32;
  if (r0 >= t.K) return;
  const int c0 = blockIdx.x * 32;
  __shared__ float tile[32][33];
  const int x = threadIdx.x, y = threadIdx.y;
  #pragma unroll
  for (int k = 0; k < 4; ++k)
    tile[y + 8*k][x] = t.s[(size_t)(r0 + y + 8*k) * 1536 + c0 + x];
  __syncthreads();
  #pragma unroll
  for (int k = 0; k < 4; ++k)
    t.d[(size_t)(c0 + y + 8*k) * t.K + r0 + x] = f2bf(tile[x][y + 8*k]);
}

// in: [R][C] bf16 -> out: [C][R] bf16
__global__ __launch_bounds__(256) void k_transpose_bf(const u16* __restrict__ in,
                                                      u16* __restrict__ out, int R, int C){
  const int r0 = blockIdx.y * 32, c0 = blockIdx.x * 32;
  __shared__ u16 tile[32][34];
  const int x = threadIdx.x, y = threadIdx.y;
  #pragma unroll
  for (int k = 0; k < 4; ++k)
    tile[y + 8*k][x] = in[(size_t)(r0 + y + 8*k) * C + c0 + x];
  __syncthreads();
  #pragma unroll
  for (int k = 0; k < 4; ++k)
    out[(size_t)(c0 + y + 8*k) * R + r0 + x] = tile[x][y + 8*k];
}

// ---------------- GEMM (m97 structure): C = A[M][K] * BT[N][K]^T, fused N-segments ----------------

struct GOuts { void* C[3]; const float* b[3]; };

template<int OUTF32>
__global__ __launch_bounds__(256, 2) void k_gemm(
  const u16* __restrict__ A, int lda,
  const u16* __restrict__ BT, int ldb,
  GOuts o, int ldc, int M, int N, int K)
{
  __shared__ alignas(1024) u16 As[128 * 64];
  __shared__ alignas(1024) u16 Bs[128 * 64];
  const int tid = threadIdx.x, lane = tid & 63, w = tid >> 6;
  const int l15 = lane & 15, l4 = lane >> 4;
  const int m0 = blockIdx.y * 128, n0 = blockIdx.x * 128;
  const int wm = (w >> 1) * 64, wn = (w & 1) * 64;

  f32x4 acc[4][4];
  #pragma unroll
  for (int i = 0; i < 4; ++i)
    #pragma unroll
    for (int j = 0; j < 4; ++j)
      acc[i][j] = (f32x4){0.f, 0.f, 0.f, 0.f};

  const int srow = w * 8 + (lane >> 3);
  const int scb  = (lane & 7) * 16;

  for (int k0 = 0; k0 < K; k0 += 64){
    #pragma unroll
    for (int c = 0; c < 4; ++c){
      const int dr = c * 32 + srow;
      const int cb = scb ^ ((dr & 7) << 4);          // pre-swizzled global source
      const int ar = min(m0 + dr, M - 1);
      gload16(A + (size_t)ar * lda + k0 + (cb >> 1), &As[c * 2048 + w * 512]);
      const int br = min(n0 + dr, N - 1);
      gload16(BT + (size_t)br * ldb + k0 + (cb >> 1), &Bs[c * 2048 + w * 512]);
    }
    asm volatile("s_waitcnt vmcnt(0)" ::: "memory");
    __syncthreads();
    #pragma unroll
    for (int kk = 0; kk < 2; ++kk){
      const int kb = (kk * 64 + l4 * 16) ^ ((l15 & 7) << 4);  // swizzled read (undoes source swz)
      bf16x8 a[4], b[4];
      #pragma unroll
      for (int m = 0; m < 4; ++m)
        a[m] = *(const bf16x8*)((const char*)As + (wm + m*16 + l15) * 128 + kb);
      #pragma unroll
      for (int n = 0; n < 4; ++n)
        b[n] = *(const bf16x8*)((const char*)Bs + (wn + n*16 + l15) * 128 + kb);
      #pragma unroll
      for (int m = 0; m < 4; ++m)
        #pragma unroll
        for (int n = 0; n < 4; ++n)
          acc[m][n] = MFMA(a[m], b[n], acc[m][n]);
    }
    __syncthreads();
  }

  #pragma unroll
  for (int n = 0; n < 4; ++n){
    const int colg = n0 + wn + n*16 + l15;
    const int sel = colg / 1536;
    const int col = colg - sel * 1536;
    const float* bp = o.b[sel];
    const float bi = bp ? bp[col] : 0.f;
    #pragma unroll
    for (int m = 0; m < 4; ++m){
      const int row0 = m0 + wm + m*16 + l4*4;
      #pragma unroll
      for (int r = 0; r < 4; ++r){
        const int row = row0 + r;
        if (row < M){
          float val = acc[m][n][r] + bi;
          if (OUTF32) ((float*)o.C[sel])[(size_t)row * ldc + col] = val;
          else        ((u16*)o.C[sel])[(size_t)row * ldc + col] = f2bf(val);
        }
      }
    }
  }
}

// ---------------- cross attention (gated, NP=256 keys), swapped QK^T ----------------
// S = mfma(K, Q): lane&15 = q, keys in regs -> lane-local softmax rows, P stays in regs.

__global__ __launch_bounds__(256, 2) void k_cross_attn(
  const u16* __restrict__ Q,     // [*, 1536], rows 0..2047 used
  const u16* __restrict__ Kp,    // [256][1536]
  const u16* __restrict__ VpT,   // [1536][256]
  const float* __restrict__ clip,
  const float* __restrict__ Wsl, // [512]
  const float* __restrict__ bslp,
  float* __restrict__ multi)     // [2048][1536]
{
  const int h = blockIdx.y;
  const int tid = threadIdx.x, lane = tid & 63, wid = tid >> 6;
  const int l15 = lane & 15, l4 = lane >> 4;
  const int qbase = blockIdx.x * 128 + wid * 32;

  float cd = 0.f;
  for (int p = lane; p < 256; p += 64) cd += clip[p] * Wsl[256 + p];
  cd = red64_sum(cd);
  const float gate_c = cd + bslp[0];

  // per-(n4) float4 of Wsl*SCALE and clip at keys n4*16 + l4*4 + {0..3}
  float4 wslS[16], clip4[16];
  #pragma unroll
  for (int n4 = 0; n4 < 16; ++n4){
    float4 wv = *(const float4*)(Wsl + n4*16 + l4*4);
    wslS[n4] = make_float4(wv.x*SCALE, wv.y*SCALE, wv.z*SCALE, wv.w*SCALE);
    clip4[n4] = *(const float4*)(clip + n4*16 + l4*4);
  }

  for (int rb = 0; rb < 2; ++rb){
    bf16x8 qf[2];
    #pragma unroll
    for (int kk = 0; kk < 2; ++kk)
      qf[kk] = *(const bf16x8*)(Q + (size_t)(qbase + rb*16 + l15) * 1536 + h*64 + kk*32 + l4*8);

    // S raw, swapped: s[n4][r] = S[key = n4*16 + l4*4 + r][q = l15]
    f32x4 s[16];
    #pragma unroll
    for (int n4 = 0; n4 < 16; ++n4){
      const int key = n4 * 16 + l15;
      const u16* kb = Kp + (size_t)key * 1536 + h * 64 + l4 * 8;
      f32x4 t = {0.f, 0.f, 0.f, 0.f};
      t = MFMA(*(const bf16x8*)(kb), qf[0], t);
      t = MFMA(*(const bf16x8*)(kb + 32), qf[1], t);
      s[n4] = t;
    }
    // gate = sum_k (S*SCALE)*Wsl[k] + gate_c  (per q = l15)
    float gs = 0.f;
    #pragma unroll
    for (int n4 = 0; n4 < 16; ++n4){
      gs += s[n4][0] * wslS[n4].x + s[n4][1] * wslS[n4].y;
      gs += s[n4][2] * wslS[n4].z + s[n4][3] * wslS[n4].w;
    }
    const float gate = redl4_sum(gs) + gate_c;
    // e = S*SCALE + gate*clip[key]
    #pragma unroll
    for (int n4 = 0; n4 < 16; ++n4){
      s[n4][0] = fmaf(s[n4][0], SCALE, gate * clip4[n4].x);
      s[n4][1] = fmaf(s[n4][1], SCALE, gate * clip4[n4].y);
      s[n4][2] = fmaf(s[n4][2], SCALE, gate * clip4[n4].z);
      s[n4][3] = fmaf(s[n4][3], SCALE, gate * clip4[n4].w);
    }
    // softmax over 64 in-reg + 2 shfl
    float mx = -1e30f;
    #pragma unroll
    for (int n4 = 0; n4 < 16; ++n4)
      mx = fmaxf(mx, fmaxf(fmaxf(s[n4][0], s[n4][1]), fmaxf(s[n4][2], s[n4][3])));
    mx = redl4_max(mx);
    const float mL = mx * L2E;
    float ls = 0.f;
    #pragma unroll
    for (int n4 = 0; n4 < 16; ++n4)
      #pragma unroll
      for (int r = 0; r < 4; ++r){
        float p = fexp2(fmaf(s[n4][r], L2E, -mL));
        s[n4][r] = p; ls += p;
      }
    ls = redl4_sum(ls);
    const float inv = 1.f / ls;

    // PV: pa = (s[2k2][0..3], s[2k2+1][0..3]) as A-frag; V^T loaded with same slot map
    f32x4 O[4];
    #pragma unroll
    for (int nb = 0; nb < 4; ++nb) O[nb] = (f32x4){0.f, 0.f, 0.f, 0.f};
    #pragma unroll
    for (int k2 = 0; k2 < 8; ++k2){
      bf16x8 pa = { (short)f2bf(s[2*k2][0]),   (short)f2bf(s[2*k2][1]),
                    (short)f2bf(s[2*k2][2]),   (short)f2bf(s[2*k2][3]),
                    (short)f2bf(s[2*k2+1][0]), (short)f2bf(s[2*k2+1][1]),
                    (short)f2bf(s[2*k2+1][2]), (short)f2bf(s[2*k2+1][3]) };
      #pragma unroll
      for (int nb = 0; nb < 4; ++nb){
        const int d = nb*16 + l15;
        const u16* vb = VpT + (size_t)(h*64 + d) * 256 + k2*32 + l4*4;
        bf16x4 vlo = *(const bf16x4*)(vb);
        bf16x4 vhi = *(const bf16x4*)(vb + 16);
        bf16x8 vt = __builtin_shufflevector(vlo, vhi, 0,1,2,3,4,5,6,7);
        O[nb] = MFMA(pa, vt, O[nb]);
      }
    }

    float li[4];
    #pragma unroll
    for (int r = 0; r < 4; ++r) li[r] = __shfl(inv, l4*4 + r, 16);
    #pragma unroll
    for (int nb = 0; nb < 4; ++nb){
      const int col = h*64 + nb*16 + l15;
      #pragma unroll
      for (int r = 0; r < 4; ++r){
        const int row = qbase + rb*16 + l4*4 + r;
        multi[(size_t)row * 1536 + col] = O[nb][r] * li[r];
      }
    }
  }
}

// ---------------- self attention (flash, swapped QK^T, LDS K/V^T dbuf) ----------------

__global__ __launch_bounds__(256, 4) void k_self_attn(
  const u16* __restrict__ q2,   // [2304][1536]
  const u16* __restrict__ k2,   // [2304][1536]
  const u16* __restrict__ v2T,  // [1536][2304]
  float* __restrict__ hsout)    // [2202][1536]
{
  const int h = blockIdx.y;
  const int tid = threadIdx.x, lane = tid & 63, w = tid >> 6;
  const int l15 = lane & 15, l4 = lane >> 4;
  const int qrow = blockIdx.x * 64 + w * 16 + l15;

  __shared__ alignas(1024) u16 Ks[2][64 * 64];
  __shared__ alignas(1024) u16 VTs[2][64 * 64];

  bf16x8 qf[2];
  #pragma unroll
  for (int kk = 0; kk < 2; ++kk)
    qf[kk] = *(const bf16x8*)(q2 + (size_t)qrow * 1536 + h*64 + kk*32 + l4*8);

  f32x4 O[4];
  #pragma unroll
  for (int nb = 0; nb < 4; ++nb) O[nb] = (f32x4){0.f, 0.f, 0.f, 0.f};
  float m_ = -1e30f, l_ = 0.f;          // stats for q = l15
  const float C2 = SCALE * L2E;         // raw-score -> log2 domain
  const float THR = 44.36f;             // 8 / C2

  const int srow = w * 8 + (lane >> 3);
  const int scb  = (lane & 7) * 16;

  auto STAGE = [&](int buf, int kt0){
    #pragma unroll
    for (int c = 0; c < 2; ++c){
      const int r = c * 32 + srow;
      const int cb = scb ^ ((r & 7) << 4);
      gload16(k2 + (size_t)(kt0 + r) * 1536 + h*64 + (cb >> 1), &Ks[buf][c*2048 + w*512]);
      gload16(v2T + (size_t)(h*64 + r) * NPAD + kt0 + (cb >> 1), &VTs[buf][c*2048 + w*512]);
    }
  };

  STAGE(0, 0);
  asm volatile("s_waitcnt vmcnt(0)" ::: "memory");
  __syncthreads();

  int buf = 0;
  for (int nt = 0; nt < 35; ++nt){
    if (nt + 1 < 35) STAGE(buf ^ 1, (nt + 1) * 64);
    const int kt0 = nt * 64;

    // QK^T swapped: A = K rows(keys), B = Q cols(q)
    f32x4 s[4];
    __builtin_amdgcn_s_setprio(1);
    #pragma unroll
    for (int n4 = 0; n4 < 4; ++n4){
      const int key = n4 * 16 + l15;
      const char* kb = (const char*)&Ks[buf][key * 64];
      f32x4 t = {0.f, 0.f, 0.f, 0.f};
      #pragma unroll
      for (int kk = 0; kk < 2; ++kk){
        bf16x8 kf = *(const bf16x8*)(kb + ((kk*64 + l4*16) ^ ((key & 7) << 4)));
        t = MFMA(kf, qf[kk], t);
      }
      s[n4] = t;
    }
    __builtin_amdgcn_s_setprio(0);

    if (kt0 + 64 > NTOT){                       // only the last tile
      #pragma unroll
      for (int n4 = 0; n4 < 4; ++n4){
        const int keyb = kt0 + n4*16 + l4*4;
        #pragma unroll
        for (int r = 0; r < 4; ++r)
          if (keyb + r >= NTOT) s[n4][r] = -1e30f;
      }
    }

    // row stats (q = l15): in-reg max + 2 shfl
    float mt = -1e30f;
    #pragma unroll
    for (int n4 = 0; n4 < 4; ++n4)
      mt = fmaxf(mt, fmaxf(fmaxf(s[n4][0], s[n4][1]), fmaxf(s[n4][2], s[n4][3])));
    mt = redl4_max(mt);

    if (__any(mt > m_ + THR)){                  // T13 defer-max
      const float mn = fmaxf(m_, mt);
      const float al = fexp2((m_ - mn) * C2);
      m_ = mn;
      l_ *= al;
      float alo[4];
      #pragma unroll
      for (int r = 0; r < 4; ++r) alo[r] = __shfl(al, l4*4 + r, 16);
      #pragma unroll
      for (int nb = 0; nb < 4; ++nb)
        #pragma unroll
        for (int r = 0; r < 4; ++r) O[nb][r] *= alo[r];
    }
    const float m2 = m_ * C2;

    u16 pb[16];
    float ls = 0.f;
    #pragma unroll
    for (int n4 = 0; n4 < 4; ++n4)
      #pragma unroll
      for (int r = 0; r < 4; ++r){
        float p = fexp2(fmaf(s[n4][r], C2, -m2));
        ls += p;
        pb[n4*4 + r] = f2bf(p);
      }
    l_ += redl4_sum(ls);

    // PV: pa slot map pi(l4,j) = (j>>2)*16 + l4*4 + (j&3); V^T read with same map
    __builtin_amdgcn_s_setprio(1);
    #pragma unroll
    for (int kk = 0; kk < 2; ++kk){
      bf16x8 pa = { (short)pb[kk*8+0], (short)pb[kk*8+1], (short)pb[kk*8+2], (short)pb[kk*8+3],
                    (short)pb[kk*8+4], (short)pb[kk*8+5], (short)pb[kk*8+6], (short)pb[kk*8+7] };
      #pragma unroll
      for (int nb = 0; nb < 4; ++nb){
        const int d = nb * 16 + l15;
        const char* vb = (const char*)&VTs[buf][d * 64];
        const int o1 = (kk*64 + l4*8) ^ ((d & 7) << 4);
        const int o2 = (kk*64 + 32 + l4*8) ^ ((d & 7) << 4);
        bf16x4 vlo = *(const bf16x4*)(vb + o1);
        bf16x4 vhi = *(const bf16x4*)(vb + o2);
        bf16x8 vt = __builtin_shufflevector(vlo, vhi, 0,1,2,3,4,5,6,7);
        O[nb] = MFMA(pa, vt, O[nb]);
      }
    }
    __builtin_amdgcn_s_setprio(0);

    asm volatile("s_waitcnt vmcnt(0)" ::: "memory");
    __syncthreads();
    buf ^= 1;
  }

  const float inv = 1.f / l_;
  float li[4];
  #pragma unroll
  for (int r = 0; r < 4; ++r) li[r] = __shfl(inv, l4*4 + r, 16);
  #pragma unroll
  for (int r = 0; r < 4; ++r){
    const int row = blockIdx.x * 64 + w * 16 + l4*4 + r;
    if (row < NTOT){
      #pragma unroll
      for (int nb = 0; nb < 4; ++nb)
        hsout[(size_t)row * 1536 + h*64 + nb*16 + l15] = O[nb][r] * li[r];
    }
  }
}

// ---------------- adaptive gate + blend ----------------

__global__ __launch_bounds__(256) void k_adaptive(
  const float* __restrict__ multi, const float* __restrict__ hsbuf,
  const float* __restrict__ Wad, const float* __restrict__ badp,
  u16* __restrict__ blended)
{
  const int lane = threadIdx.x & 63, wid = threadIdx.x >> 6;
  const int q = blockIdx.x * 4 + wid;
  const float* mrow = multi + (size_t)q * 1536;
  const float* hrow = hsbuf + (size_t)q * 1536;
  float acc = 0.f;
  #pragma unroll
  for (int i = 0; i < 24; ++i){
    int d = lane + 64 * i;
    acc += mrow[d] * Wad[d] + hrow[d] * Wad[1536 + d];
  }
  acc = red64_sum(acc) + badp[0];
  const float sig = 1.f / (1.f + __expf(-acc));
  const float f = BLENDF * sig;
  u16* brow = blended + (size_t)q * 1536;
  #pragma unroll
  for (int i = 0; i < 24; ++i){
    int d = lane + 64 * i;
    brow[d] = f2bf(f * mrow[d] + hrow[d]);
  }
}

// ---------------- launch ----------------

extern "C" void kernel_launch(void* const* d_in, const int* in_sizes, int n_in,
                              void* d_out, int out_size, void* d_ws, size_t ws_size,
                              hipStream_t stream)
{
  (void)in_sizes; (void)n_in; (void)out_size; (void)ws_size;
  const float* hs   = (const float*)d_in[0];
  const float* enc  = (const float*)d_in[1];
  const float* pics = (const float*)d_in[2];
  const float* clip = (const float*)d_in[3];
  const float* Wq   = (const float*)d_in[4];  const float* bq   = (const float*)d_in[5];
  const float* Wk   = (const float*)d_in[6];  const float* bk   = (const float*)d_in[7];
  const float* Wv   = (const float*)d_in[8];  const float* bv   = (const float*)d_in[9];
  const float* Waq  = (const float*)d_in[10]; const float* baq  = (const float*)d_in[11];
  const float* Wak  = (const float*)d_in[12]; const float* bak  = (const float*)d_in[13];
  const float* Wav  = (const float*)d_in[14]; const float* bav  = (const float*)d_in[15];
  const float* Wkl  = (const float*)d_in[16]; const float* Wvl  = (const float*)d_in[17];
  const float* Wsl  = (const float*)d_in[18]; const float* bsl  = (const float*)d_in[19];
  const float* Wad  = (const float*)d_in[20]; const float* bad  = (const float*)d_in[21];
  const float* Wout = (const float*)d_in[22]; const float* bout = (const float*)d_in[23];
  const float* Wadd = (const float*)d_in[24]; const float* badd = (const float*)d_in[25];

  char* ws = (char*)d_ws;
  size_t off = 0;
  auto alloc = [&](size_t b){ void* p = ws + off; off += (b + 255) & ~(size_t)255; return p; };

  u16* hs_bf  = (u16*)alloc((size_t)2048*1536*2);
  u16* enc_bf = (u16*)alloc((size_t)154*1536*2);
  u16* pics_bf= (u16*)alloc((size_t)256*1024*2);
  u16* WqT  = (u16*)alloc((size_t)1536*1536*2);
  u16* WkT  = (u16*)alloc((size_t)1536*1536*2);
  u16* WvT  = (u16*)alloc((size_t)1536*1536*2);
  u16* WaqT = (u16*)alloc((size_t)1536*1536*2);
  u16* WakT = (u16*)alloc((size_t)1536*1536*2);
  u16* WavT = (u16*)alloc((size_t)1536*1536*2);
  u16* WoutT= (u16*)alloc((size_t)1536*1536*2);
  u16* WaddT= (u16*)alloc((size_t)1536*1536*2);
  u16* WklT = (u16*)alloc((size_t)1536*1024*2);
  u16* WvlT = (u16*)alloc((size_t)1536*1024*2);
  u16* q2   = (u16*)alloc((size_t)NPAD*1536*2);
  u16* k2   = (u16*)alloc((size_t)NPAD*1536*2);
  u16* v2   = (u16*)alloc((size_t)NPAD*1536*2);
  u16* v2T  = (u16*)alloc((size_t)1536*NPAD*2);
  u16* Kp   = (u16*)alloc((size_t)256*1536*2);
  u16* Vp   = (u16*)alloc((size_t)256*1536*2);
  u16* VpT  = (u16*)alloc((size_t)1536*256*2);
  float* multi  = (float*)alloc((size_t)2048*1536*4);
  float* hsbuf  = (float*)alloc((size_t)NTOT*1536*4);
  u16* blended  = (u16*)alloc((size_t)2048*1536*2);
  u16* hstxt    = (u16*)alloc((size_t)154*1536*2);

  const long padn8 = ((long)(NPAD - NTOT) * 1536) / 8;   // 19584
  k_zeropad<<<dim3((padn8 + 255) / 256), 256, 0, stream>>>(
      q2 + (size_t)NTOT*1536, k2 + (size_t)NTOT*1536, v2 + (size_t)NTOT*1536, padn8);

  k_cast<<<dim3(3072), 256, 0, stream>>>(hs,   hs_bf,  (long)2048*1536);
  k_cast<<<dim3(231),  256, 0, stream>>>(enc,  enc_bf, (long)154*1536);
  k_cast<<<dim3(256),  256, 0, stream>>>(pics, pics_bf,(long)256*1024);

  WT10 wts;
  wts.w[0] = {Wq,   WqT,   1536};
  wts.w[1] = {Wk,   WkT,   1536};
  wts.w[2] = {Wv,   WvT,   1536};
  wts.w[3] = {Waq,  WaqT,  1536};
  wts.w[4] = {Wak,  WakT,  1536};
  wts.w[5] = {Wav,  WavT,  1536};
  wts.w[6] = {Wout, WoutT, 1536};
  wts.w[7] = {Wadd, WaddT, 1536};
  wts.w[8] = {Wkl,  WklT,  1024};
  wts.w[9] = {Wvl,  WvlT,  1024};
  k_transpose_w<<<dim3(48, 48, 10), dim3(32, 8), 0, stream>>>(wts);

  GOuts oqkv; oqkv.C[0] = q2; oqkv.C[1] = k2; oqkv.C[2] = v2;
  oqkv.b[0] = bq; oqkv.b[1] = bk; oqkv.b[2] = bv;
  k_gemm<0><<<dim3(36, 16), 256, 0, stream>>>(hs_bf, 1536, WqT, 1536, oqkv, 1536, 2048, 4608, 1536);

  GOuts oenc; oenc.C[0] = q2 + (size_t)2048*1536; oenc.C[1] = k2 + (size_t)2048*1536; oenc.C[2] = v2 + (size_t)2048*1536;
  oenc.b[0] = baq; oenc.b[1] = bak; oenc.b[2] = bav;
  k_gemm<0><<<dim3(36, 2), 256, 0, stream>>>(enc_bf, 1536, WaqT, 1536, oenc, 1536, 154, 4608, 1536);

  GOuts okv; okv.C[0] = Kp; okv.C[1] = Vp; okv.C[2] = nullptr;
  okv.b[0] = nullptr; okv.b[1] = nullptr; okv.b[2] = nullptr;
  k_gemm<0><<<dim3(24, 2), 256, 0, stream>>>(pics_bf, 1024, WklT, 1024, okv, 1536, 256, 3072, 1024);

  k_transpose_bf<<<dim3(48, NPAD/32), dim3(32, 8), 0, stream>>>(v2, v2T, NPAD, 1536);
  k_transpose_bf<<<dim3(48, 8),       dim3(32, 8), 0, stream>>>(Vp, VpT, 256, 1536);

  k_cross_attn<<<dim3(16, 24), 256, 0, stream>>>(q2, Kp, VpT, clip, Wsl, bsl, multi);
  k_self_attn<<<dim3(35, 24), 256, 0, stream>>>(q2, k2, v2T, hsbuf);

  k_adaptive<<<dim3(512), 256, 0, stream>>>(multi, hsbuf, Wad, bad, blended);
  k_cast<<<dim3(231), 256, 0, stream>>>(hsbuf + (size_t)2048*1536, hstxt, (long)154*1536);

  GOuts oout; oout.C[0] = d_out; oout.C[1] = nullptr; oout.C[2] = nullptr;
  oout.b[0] = bout; oout.b[1] = nullptr; oout.b[2] = nullptr;
  k_gemm<1><<<dim3(12, 16), 256, 0, stream>>>(blended, 1536, WoutT, 1536, oout, 1536, 2048, 1536, 1536);

  GOuts oadd; oadd.C[0] = (float*)d_out + (size_t)2048*1536; oadd.C[1] = nullptr; oadd.C[2] = nullptr;
  oadd.b[0] = badd; oadd.b[1] = nullptr; oadd.b[2] = nullptr;
  k_gemm<1><<<dim3(12, 2), 256, 0, stream>>>(hstxt, 1536, WaddT, 1536, oadd, 1536, 154, 1536, 1536);
}

// Round 4
// 399.305 us; speedup vs baseline: 2.9401x; 1.0036x over previous
//
#include <hip/hip_runtime.h>

typedef unsigned short u16;
typedef unsigned int u32;
typedef __attribute__((ext_vector_type(4))) short bf16x4;
typedef __attribute__((ext_vector_type(8))) short bf16x8;
typedef __attribute__((ext_vector_type(4))) float f32x4;

#define SCALE 0.125f
#define BLENDF 0.4875f
#define NTOT 2202
#define NPAD 2304
#define L2E 1.44269504f

__device__ __forceinline__ u16 f2bf(float x){
  union { float f; unsigned u; } v; v.f = x;
  unsigned r = v.u + 0x7fffu + ((v.u >> 16) & 1u);
  return (u16)(r >> 16);
}

__device__ __forceinline__ float fexp2(float x){
#if __has_builtin(__builtin_amdgcn_exp2f)
  return __builtin_amdgcn_exp2f(x);
#else
  return __expf(x * 0.6931472f);
#endif
}

__device__ __forceinline__ f32x4 MFMA(bf16x8 a, bf16x8 b, f32x4 c){
  return __builtin_amdgcn_mfma_f32_16x16x32_bf16(a, b, c, 0, 0, 0);
}

// async global->LDS, 16B per lane; LDS dest is wave-uniform base (+lane*16 implicit)
__device__ __forceinline__ void gload16(const u16* g, u16* l){
  __builtin_amdgcn_global_load_lds(
    (const __attribute__((address_space(1))) u32*)g,
    (__attribute__((address_space(3))) u32*)l, 16, 0, 0);
}

__device__ __forceinline__ float red64_sum(float x){
  x += __shfl_xor(x, 1, 64);
  x += __shfl_xor(x, 2, 64);
  x += __shfl_xor(x, 4, 64);
  x += __shfl_xor(x, 8, 64);
  x += __shfl_xor(x, 16, 64);
  x += __shfl_xor(x, 32, 64);
  return x;
}
// reduce over the l4 axis (lanes sharing the same lane&15)
__device__ __forceinline__ float redl4_sum(float x){
  x += __shfl_xor(x, 16, 64);
  x += __shfl_xor(x, 32, 64);
  return x;
}
__device__ __forceinline__ float redl4_max(float x){
  x = fmaxf(x, __shfl_xor(x, 16, 64));
  x = fmaxf(x, __shfl_xor(x, 32, 64));
  return x;
}

// ---------------- utility kernels ----------------

__global__ void k_zeropad(u16* __restrict__ a, u16* __restrict__ b,
                          u16* __restrict__ c, long n8){
  long i = (long)blockIdx.x * blockDim.x + threadIdx.x;
  if (i < n8){
    const bf16x8 z = {0,0,0,0,0,0,0,0};
    *(bf16x8*)(a + i*8) = z;
    *(bf16x8*)(b + i*8) = z;
    *(bf16x8*)(c + i*8) = z;
  }
}

__global__ void k_cast(const float* __restrict__ in, u16* __restrict__ out, long n){
  long i = ((long)blockIdx.x * blockDim.x + threadIdx.x) * 4;
  long stride = (long)gridDim.x * blockDim.x * 4;
  for (; i < n; i += stride){
    float4 f = *(const float4*)(in + i);
    bf16x4 v = { (short)f2bf(f.x), (short)f2bf(f.y), (short)f2bf(f.z), (short)f2bf(f.w) };
    *(bf16x4*)(out + i) = v;
  }
}

struct WT { const float* s; u16* d; int K; };
struct WT10 { WT w[10]; };

// in: [K][1536] fp32 -> out: [1536][K] bf16
__global__ __launch_bounds__(256) void k_transpose_w(WT10 ws){
  const WT t = ws.w[blockIdx.z];
  const int r0 = blockIdx.y * 32;
  if (r0 >= t.K) return;
  const int c0 = blockIdx.x * 32;
  __shared__ float tile[32][33];
  const int x = threadIdx.x, y = threadIdx.y;
  #pragma unroll
  for (int k = 0; k < 4; ++k)
    tile[y + 8*k][x] = t.s[(size_t)(r0 + y + 8*k) * 1536 + c0 + x];
  __syncthreads();
  #pragma unroll
  for (int k = 0; k < 4; ++k)
    t.d[(size_t)(c0 + y + 8*k) * t.K + r0 + x] = f2bf(tile[x][y + 8*k]);
}

// in: [R][C] bf16 -> out: [C][R] bf16
__global__ __launch_bounds__(256) void k_transpose_bf(const u16* __restrict__ in,
                                                      u16* __restrict__ out, int R, int C){
  const int r0 = blockIdx.y * 32, c0 = blockIdx.x * 32;
  __shared__ u16 tile[32][34];
  const int x = threadIdx.x, y = threadIdx.y;
  #pragma unroll
  for (int k = 0; k < 4; ++k)
    tile[y + 8*k][x] = in[(size_t)(r0 + y + 8*k) * C + c0 + x];
  __syncthreads();
  #pragma unroll
  for (int k = 0; k < 4; ++k)
    out[(size_t)(c0 + y + 8*k) * R + r0 + x] = tile[x][y + 8*k];
}

// ---------------- GEMM (m97 structure): C = A[M][K] * BT[N][K]^T, fused N-segments ----------------

struct GOuts { void* C[3]; const float* b[3]; };

template<int OUTF32>
__global__ __launch_bounds__(256, 2) void k_gemm(
  const u16* __restrict__ A, int lda,
  const u16* __restrict__ BT, int ldb,
  GOuts o, int ldc, int M, int N, int K)
{
  __shared__ alignas(1024) u16 As[128 * 64];
  __shared__ alignas(1024) u16 Bs[128 * 64];
  const int tid = threadIdx.x, lane = tid & 63, w = tid >> 6;
  const int l15 = lane & 15, l4 = lane >> 4;
  const int m0 = blockIdx.y * 128, n0 = blockIdx.x * 128;
  const int wm = (w >> 1) * 64, wn = (w & 1) * 64;

  f32x4 acc[4][4];
  #pragma unroll
  for (int i = 0; i < 4; ++i)
    #pragma unroll
    for (int j = 0; j < 4; ++j)
      acc[i][j] = (f32x4){0.f, 0.f, 0.f, 0.f};

  const int srow = w * 8 + (lane >> 3);
  const int scb  = (lane & 7) * 16;

  for (int k0 = 0; k0 < K; k0 += 64){
    #pragma unroll
    for (int c = 0; c < 4; ++c){
      const int dr = c * 32 + srow;
      const int cb = scb ^ ((dr & 7) << 4);          // pre-swizzled global source
      const int ar = min(m0 + dr, M - 1);
      gload16(A + (size_t)ar * lda + k0 + (cb >> 1), &As[c * 2048 + w * 512]);
      const int br = min(n0 + dr, N - 1);
      gload16(BT + (size_t)br * ldb + k0 + (cb >> 1), &Bs[c * 2048 + w * 512]);
    }
    asm volatile("s_waitcnt vmcnt(0)" ::: "memory");
    __syncthreads();
    #pragma unroll
    for (int kk = 0; kk < 2; ++kk){
      const int kb = (kk * 64 + l4 * 16) ^ ((l15 & 7) << 4);  // swizzled read (undoes source swz)
      bf16x8 a[4], b[4];
      #pragma unroll
      for (int m = 0; m < 4; ++m)
        a[m] = *(const bf16x8*)((const char*)As + (wm + m*16 + l15) * 128 + kb);
      #pragma unroll
      for (int n = 0; n < 4; ++n)
        b[n] = *(const bf16x8*)((const char*)Bs + (wn + n*16 + l15) * 128 + kb);
      #pragma unroll
      for (int m = 0; m < 4; ++m)
        #pragma unroll
        for (int n = 0; n < 4; ++n)
          acc[m][n] = MFMA(a[m], b[n], acc[m][n]);
    }
    __syncthreads();
  }

  #pragma unroll
  for (int n = 0; n < 4; ++n){
    const int colg = n0 + wn + n*16 + l15;
    const int sel = colg / 1536;
    const int col = colg - sel * 1536;
    const float* bp = o.b[sel];
    const float bi = bp ? bp[col] : 0.f;
    #pragma unroll
    for (int m = 0; m < 4; ++m){
      const int row0 = m0 + wm + m*16 + l4*4;
      #pragma unroll
      for (int r = 0; r < 4; ++r){
        const int row = row0 + r;
        if (row < M){
          float val = acc[m][n][r] + bi;
          if (OUTF32) ((float*)o.C[sel])[(size_t)row * ldc + col] = val;
          else        ((u16*)o.C[sel])[(size_t)row * ldc + col] = f2bf(val);
        }
      }
    }
  }
}

// ---------------- cross attention (gated, NP=256 keys), swapped QK^T ----------------
// S = mfma(K, Q): lane&15 = q, keys in regs -> lane-local softmax rows, P stays in regs.
// Wsl*SCALE and clip live in LDS (NOT registers: 128-VGPR preload spilled in r3).

__global__ __launch_bounds__(256, 2) void k_cross_attn(
  const u16* __restrict__ Q,     // [*, 1536], rows 0..2047 used
  const u16* __restrict__ Kp,    // [256][1536]
  const u16* __restrict__ VpT,   // [1536][256]
  const float* __restrict__ clip,
  const float* __restrict__ Wsl, // [512]
  const float* __restrict__ bslp,
  float* __restrict__ multi)     // [2048][1536]
{
  const int h = blockIdx.y;
  const int tid = threadIdx.x, lane = tid & 63, wid = tid >> 6;
  const int l15 = lane & 15, l4 = lane >> 4;
  const int qbase = blockIdx.x * 128 + wid * 32;

  __shared__ float wslS_l[256];
  __shared__ float clip_l[256];
  if (tid < 256){
    wslS_l[tid] = Wsl[tid] * SCALE;
    clip_l[tid] = clip[tid];
  }

  float cd = 0.f;
  for (int p = lane; p < 256; p += 64) cd += clip[p] * Wsl[256 + p];
  cd = red64_sum(cd);
  const float gate_c = cd + bslp[0];
  __syncthreads();

  for (int rb = 0; rb < 2; ++rb){
    bf16x8 qf[2];
    #pragma unroll
    for (int kk = 0; kk < 2; ++kk)
      qf[kk] = *(const bf16x8*)(Q + (size_t)(qbase + rb*16 + l15) * 1536 + h*64 + kk*32 + l4*8);

    // S raw, swapped: s[n4][r] = S[key = n4*16 + l4*4 + r][q = l15]
    f32x4 s[16];
    #pragma unroll
    for (int n4 = 0; n4 < 16; ++n4){
      const int key = n4 * 16 + l15;
      const u16* kb = Kp + (size_t)key * 1536 + h * 64 + l4 * 8;
      f32x4 t = {0.f, 0.f, 0.f, 0.f};
      t = MFMA(*(const bf16x8*)(kb), qf[0], t);
      t = MFMA(*(const bf16x8*)(kb + 32), qf[1], t);
      s[n4] = t;
    }
    // gate = sum_k (S*SCALE)*Wsl[k] + gate_c  (per q = l15)
    float gs = 0.f;
    #pragma unroll
    for (int n4 = 0; n4 < 16; ++n4){
      const float4 wv = *(const float4*)&wslS_l[n4*16 + l4*4];
      gs += s[n4][0] * wv.x + s[n4][1] * wv.y;
      gs += s[n4][2] * wv.z + s[n4][3] * wv.w;
    }
    const float gate = redl4_sum(gs) + gate_c;
    // e = S*SCALE + gate*clip[key]
    #pragma unroll
    for (int n4 = 0; n4 < 16; ++n4){
      const float4 cv = *(const float4*)&clip_l[n4*16 + l4*4];
      s[n4][0] = fmaf(s[n4][0], SCALE, gate * cv.x);
      s[n4][1] = fmaf(s[n4][1], SCALE, gate * cv.y);
      s[n4][2] = fmaf(s[n4][2], SCALE, gate * cv.z);
      s[n4][3] = fmaf(s[n4][3], SCALE, gate * cv.w);
    }
    // softmax over 64 in-reg + 2 shfl
    float mx = -1e30f;
    #pragma unroll
    for (int n4 = 0; n4 < 16; ++n4)
      mx = fmaxf(mx, fmaxf(fmaxf(s[n4][0], s[n4][1]), fmaxf(s[n4][2], s[n4][3])));
    mx = redl4_max(mx);
    const float mL = mx * L2E;
    float ls = 0.f;
    #pragma unroll
    for (int n4 = 0; n4 < 16; ++n4)
      #pragma unroll
      for (int r = 0; r < 4; ++r){
        float p = fexp2(fmaf(s[n4][r], L2E, -mL));
        s[n4][r] = p; ls += p;
      }
    ls = redl4_sum(ls);
    const float inv = 1.f / ls;

    // PV: pa = (s[2k2][0..3], s[2k2+1][0..3]) as A-frag; V^T loaded with same slot map
    f32x4 O[4];
    #pragma unroll
    for (int nb = 0; nb < 4; ++nb) O[nb] = (f32x4){0.f, 0.f, 0.f, 0.f};
    #pragma unroll
    for (int k2 = 0; k2 < 8; ++k2){
      bf16x8 pa = { (short)f2bf(s[2*k2][0]),   (short)f2bf(s[2*k2][1]),
                    (short)f2bf(s[2*k2][2]),   (short)f2bf(s[2*k2][3]),
                    (short)f2bf(s[2*k2+1][0]), (short)f2bf(s[2*k2+1][1]),
                    (short)f2bf(s[2*k2+1][2]), (short)f2bf(s[2*k2+1][3]) };
      #pragma unroll
      for (int nb = 0; nb < 4; ++nb){
        const int d = nb*16 + l15;
        const u16* vb = VpT + (size_t)(h*64 + d) * 256 + k2*32 + l4*4;
        bf16x4 vlo = *(const bf16x4*)(vb);
        bf16x4 vhi = *(const bf16x4*)(vb + 16);
        bf16x8 vt = __builtin_shufflevector(vlo, vhi, 0,1,2,3,4,5,6,7);
        O[nb] = MFMA(pa, vt, O[nb]);
      }
    }

    float li[4];
    #pragma unroll
    for (int r = 0; r < 4; ++r) li[r] = __shfl(inv, l4*4 + r, 16);
    #pragma unroll
    for (int nb = 0; nb < 4; ++nb){
      const int col = h*64 + nb*16 + l15;
      #pragma unroll
      for (int r = 0; r < 4; ++r){
        const int row = qbase + rb*16 + l4*4 + r;
        multi[(size_t)row * 1536 + col] = O[nb][r] * li[r];
      }
    }
  }
}

// ---------------- self attention (flash, swapped QK^T, LDS K/V^T dbuf) ----------------

__global__ __launch_bounds__(256, 4) void k_self_attn(
  const u16* __restrict__ q2,   // [2304][1536]
  const u16* __restrict__ k2,   // [2304][1536]
  const u16* __restrict__ v2T,  // [1536][2304]
  float* __restrict__ hsout)    // [2202][1536]
{
  const int h = blockIdx.y;
  const int tid = threadIdx.x, lane = tid & 63, w = tid >> 6;
  const int l15 = lane & 15, l4 = lane >> 4;
  const int qrow = blockIdx.x * 64 + w * 16 + l15;

  __shared__ alignas(1024) u16 Ks[2][64 * 64];
  __shared__ alignas(1024) u16 VTs[2][64 * 64];

  bf16x8 qf[2];
  #pragma unroll
  for (int kk = 0; kk < 2; ++kk)
    qf[kk] = *(const bf16x8*)(q2 + (size_t)qrow * 1536 + h*64 + kk*32 + l4*8);

  f32x4 O[4];
  #pragma unroll
  for (int nb = 0; nb < 4; ++nb) O[nb] = (f32x4){0.f, 0.f, 0.f, 0.f};
  float m_ = -1e30f, l_ = 0.f;          // stats for q = l15
  const float C2 = SCALE * L2E;         // raw-score -> log2 domain
  const float THR = 44.36f;             // 8 / C2

  const int srow = w * 8 + (lane >> 3);
  const int scb  = (lane & 7) * 16;

  auto STAGE = [&](int buf, int kt0){
    #pragma unroll
    for (int c = 0; c < 2; ++c){
      const int r = c * 32 + srow;
      const int cb = scb ^ ((r & 7) << 4);
      gload16(k2 + (size_t)(kt0 + r) * 1536 + h*64 + (cb >> 1), &Ks[buf][c*2048 + w*512]);
      gload16(v2T + (size_t)(h*64 + r) * NPAD + kt0 + (cb >> 1), &VTs[buf][c*2048 + w*512]);
    }
  };

  STAGE(0, 0);
  asm volatile("s_waitcnt vmcnt(0)" ::: "memory");
  __syncthreads();

  int buf = 0;
  for (int nt = 0; nt < 35; ++nt){
    if (nt + 1 < 35) STAGE(buf ^ 1, (nt + 1) * 64);
    const int kt0 = nt * 64;

    // QK^T swapped: A = K rows(keys), B = Q cols(q)
    f32x4 s[4];
    __builtin_amdgcn_s_setprio(1);
    #pragma unroll
    for (int n4 = 0; n4 < 4; ++n4){
      const int key = n4 * 16 + l15;
      const char* kb = (const char*)&Ks[buf][key * 64];
      f32x4 t = {0.f, 0.f, 0.f, 0.f};
      #pragma unroll
      for (int kk = 0; kk < 2; ++kk){
        bf16x8 kf = *(const bf16x8*)(kb + ((kk*64 + l4*16) ^ ((key & 7) << 4)));
        t = MFMA(kf, qf[kk], t);
      }
      s[n4] = t;
    }
    __builtin_amdgcn_s_setprio(0);

    if (kt0 + 64 > NTOT){                       // only the last tile
      #pragma unroll
      for (int n4 = 0; n4 < 4; ++n4){
        const int keyb = kt0 + n4*16 + l4*4;
        #pragma unroll
        for (int r = 0; r < 4; ++r)
          if (keyb + r >= NTOT) s[n4][r] = -1e30f;
      }
    }

    // row stats (q = l15): in-reg max + 2 shfl
    float mt = -1e30f;
    #pragma unroll
    for (int n4 = 0; n4 < 4; ++n4)
      mt = fmaxf(mt, fmaxf(fmaxf(s[n4][0], s[n4][1]), fmaxf(s[n4][2], s[n4][3])));
    mt = redl4_max(mt);

    if (__any(mt > m_ + THR)){                  // T13 defer-max
      const float mn = fmaxf(m_, mt);
      const float al = fexp2((m_ - mn) * C2);
      m_ = mn;
      l_ *= al;
      float alo[4];
      #pragma unroll
      for (int r = 0; r < 4; ++r) alo[r] = __shfl(al, l4*4 + r, 16);
      #pragma unroll
      for (int nb = 0; nb < 4; ++nb)
        #pragma unroll
        for (int r = 0; r < 4; ++r) O[nb][r] *= alo[r];
    }
    const float m2 = m_ * C2;

    u16 pb[16];
    float ls = 0.f;
    #pragma unroll
    for (int n4 = 0; n4 < 4; ++n4)
      #pragma unroll
      for (int r = 0; r < 4; ++r){
        float p = fexp2(fmaf(s[n4][r], C2, -m2));
        ls += p;
        pb[n4*4 + r] = f2bf(p);
      }
    l_ += redl4_sum(ls);

    // PV: pa slot map pi(l4,j) = (j>>2)*16 + l4*4 + (j&3); V^T read with same map
    __builtin_amdgcn_s_setprio(1);
    #pragma unroll
    for (int kk = 0; kk < 2; ++kk){
      bf16x8 pa = { (short)pb[kk*8+0], (short)pb[kk*8+1], (short)pb[kk*8+2], (short)pb[kk*8+3],
                    (short)pb[kk*8+4], (short)pb[kk*8+5], (short)pb[kk*8+6], (short)pb[kk*8+7] };
      #pragma unroll
      for (int nb = 0; nb < 4; ++nb){
        const int d = nb * 16 + l15;
        const char* vb = (const char*)&VTs[buf][d * 64];
        const int o1 = (kk*64 + l4*8) ^ ((d & 7) << 4);
        const int o2 = (kk*64 + 32 + l4*8) ^ ((d & 7) << 4);
        bf16x4 vlo = *(const bf16x4*)(vb + o1);
        bf16x4 vhi = *(const bf16x4*)(vb + o2);
        bf16x8 vt = __builtin_shufflevector(vlo, vhi, 0,1,2,3,4,5,6,7);
        O[nb] = MFMA(pa, vt, O[nb]);
      }
    }
    __builtin_amdgcn_s_setprio(0);

    asm volatile("s_waitcnt vmcnt(0)" ::: "memory");
    __syncthreads();
    buf ^= 1;
  }

  const float inv = 1.f / l_;
  float li[4];
  #pragma unroll
  for (int r = 0; r < 4; ++r) li[r] = __shfl(inv, l4*4 + r, 16);
  #pragma unroll
  for (int r = 0; r < 4; ++r){
    const int row = blockIdx.x * 64 + w * 16 + l4*4 + r;
    if (row < NTOT){
      #pragma unroll
      for (int nb = 0; nb < 4; ++nb)
        hsout[(size_t)row * 1536 + h*64 + nb*16 + l15] = O[nb][r] * li[r];
    }
  }
}

// ---------------- adaptive gate + blend ----------------

__global__ __launch_bounds__(256) void k_adaptive(
  const float* __restrict__ multi, const float* __restrict__ hsbuf,
  const float* __restrict__ Wad, const float* __restrict__ badp,
  u16* __restrict__ blended)
{
  const int lane = threadIdx.x & 63, wid = threadIdx.x >> 6;
  const int q = blockIdx.x * 4 + wid;
  const float* mrow = multi + (size_t)q * 1536;
  const float* hrow = hsbuf + (size_t)q * 1536;
  float acc = 0.f;
  #pragma unroll
  for (int i = 0; i < 24; ++i){
    int d = lane + 64 * i;
    acc += mrow[d] * Wad[d] + hrow[d] * Wad[1536 + d];
  }
  acc = red64_sum(acc) + badp[0];
  const float sig = 1.f / (1.f + __expf(-acc));
  const float f = BLENDF * sig;
  u16* brow = blended + (size_t)q * 1536;
  #pragma unroll
  for (int i = 0; i < 24; ++i){
    int d = lane + 64 * i;
    brow[d] = f2bf(f * mrow[d] + hrow[d]);
  }
}

// ---------------- launch ----------------

extern "C" void kernel_launch(void* const* d_in, const int* in_sizes, int n_in,
                              void* d_out, int out_size, void* d_ws, size_t ws_size,
                              hipStream_t stream)
{
  (void)in_sizes; (void)n_in; (void)out_size; (void)ws_size;
  const float* hs   = (const float*)d_in[0];
  const float* enc  = (const float*)d_in[1];
  const float* pics = (const float*)d_in[2];
  const float* clip = (const float*)d_in[3];
  const float* Wq   = (const float*)d_in[4];  const float* bq   = (const float*)d_in[5];
  const float* Wk   = (const float*)d_in[6];  const float* bk   = (const float*)d_in[7];
  const float* Wv   = (const float*)d_in[8];  const float* bv   = (const float*)d_in[9];
  const float* Waq  = (const float*)d_in[10]; const float* baq  = (const float*)d_in[11];
  const float* Wak  = (const float*)d_in[12]; const float* bak  = (const float*)d_in[13];
  const float* Wav  = (const float*)d_in[14]; const float* bav  = (const float*)d_in[15];
  const float* Wkl  = (const float*)d_in[16]; const float* Wvl  = (const float*)d_in[17];
  const float* Wsl  = (const float*)d_in[18]; const float* bsl  = (const float*)d_in[19];
  const float* Wad  = (const float*)d_in[20]; const float* bad  = (const float*)d_in[21];
  const float* Wout = (const float*)d_in[22]; const float* bout = (const float*)d_in[23];
  const float* Wadd = (const float*)d_in[24]; const float* badd = (const float*)d_in[25];

  char* ws = (char*)d_ws;
  size_t off = 0;
  auto alloc = [&](size_t b){ void* p = ws + off; off += (b + 255) & ~(size_t)255; return p; };

  u16* hs_bf  = (u16*)alloc((size_t)2048*1536*2);
  u16* enc_bf = (u16*)alloc((size_t)154*1536*2);
  u16* pics_bf= (u16*)alloc((size_t)256*1024*2);
  u16* WqT  = (u16*)alloc((size_t)1536*1536*2);
  u16* WkT  = (u16*)alloc((size_t)1536*1536*2);
  u16* WvT  = (u16*)alloc((size_t)1536*1536*2);
  u16* WaqT = (u16*)alloc((size_t)1536*1536*2);
  u16* WakT = (u16*)alloc((size_t)1536*1536*2);
  u16* WavT = (u16*)alloc((size_t)1536*1536*2);
  u16* WoutT= (u16*)alloc((size_t)1536*1536*2);
  u16* WaddT= (u16*)alloc((size_t)1536*1536*2);
  u16* WklT = (u16*)alloc((size_t)1536*1024*2);
  u16* WvlT = (u16*)alloc((size_t)1536*1024*2);
  u16* q2   = (u16*)alloc((size_t)NPAD*1536*2);
  u16* k2   = (u16*)alloc((size_t)NPAD*1536*2);
  u16* v2   = (u16*)alloc((size_t)NPAD*1536*2);
  u16* v2T  = (u16*)alloc((size_t)1536*NPAD*2);
  u16* Kp   = (u16*)alloc((size_t)256*1536*2);
  u16* Vp   = (u16*)alloc((size_t)256*1536*2);
  u16* VpT  = (u16*)alloc((size_t)1536*256*2);
  float* multi  = (float*)alloc((size_t)2048*1536*4);
  float* hsbuf  = (float*)alloc((size_t)NTOT*1536*4);
  u16* blended  = (u16*)alloc((size_t)2048*1536*2);
  u16* hstxt    = (u16*)alloc((size_t)154*1536*2);

  const long padn8 = ((long)(NPAD - NTOT) * 1536) / 8;   // 19584
  k_zeropad<<<dim3((padn8 + 255) / 256), 256, 0, stream>>>(
      q2 + (size_t)NTOT*1536, k2 + (size_t)NTOT*1536, v2 + (size_t)NTOT*1536, padn8);

  k_cast<<<dim3(3072), 256, 0, stream>>>(hs,   hs_bf,  (long)2048*1536);
  k_cast<<<dim3(231),  256, 0, stream>>>(enc,  enc_bf, (long)154*1536);
  k_cast<<<dim3(256),  256, 0, stream>>>(pics, pics_bf,(long)256*1024);

  WT10 wts;
  wts.w[0] = {Wq,   WqT,   1536};
  wts.w[1] = {Wk,   WkT,   1536};
  wts.w[2] = {Wv,   WvT,   1536};
  wts.w[3] = {Waq,  WaqT,  1536};
  wts.w[4] = {Wak,  WakT,  1536};
  wts.w[5] = {Wav,  WavT,  1536};
  wts.w[6] = {Wout, WoutT, 1536};
  wts.w[7] = {Wadd, WaddT, 1536};
  wts.w[8] = {Wkl,  WklT,  1024};
  wts.w[9] = {Wvl,  WvlT,  1024};
  k_transpose_w<<<dim3(48, 48, 10), dim3(32, 8), 0, stream>>>(wts);

  GOuts oqkv; oqkv.C[0] = q2; oqkv.C[1] = k2; oqkv.C[2] = v2;
  oqkv.b[0] = bq; oqkv.b[1] = bk; oqkv.b[2] = bv;
  k_gemm<0><<<dim3(36, 16), 256, 0, stream>>>(hs_bf, 1536, WqT, 1536, oqkv, 1536, 2048, 4608, 1536);

  GOuts oenc; oenc.C[0] = q2 + (size_t)2048*1536; oenc.C[1] = k2 + (size_t)2048*1536; oenc.C[2] = v2 + (size_t)2048*1536;
  oenc.b[0] = baq; oenc.b[1] = bak; oenc.b[2] = bav;
  k_gemm<0><<<dim3(36, 2), 256, 0, stream>>>(enc_bf, 1536, WaqT, 1536, oenc, 1536, 154, 4608, 1536);

  GOuts okv; okv.C[0] = Kp; okv.C[1] = Vp; okv.C[2] = nullptr;
  okv.b[0] = nullptr; okv.b[1] = nullptr; okv.b[2] = nullptr;
  k_gemm<0><<<dim3(24, 2), 256, 0, stream>>>(pics_bf, 1024, WklT, 1024, okv, 1536, 256, 3072, 1024);

  k_transpose_bf<<<dim3(48, NPAD/32), dim3(32, 8), 0, stream>>>(v2, v2T, NPAD, 1536);
  k_transpose_bf<<<dim3(48, 8),       dim3(32, 8), 0, stream>>>(Vp, VpT, 256, 1536);

  k_cross_attn<<<dim3(16, 24), 256, 0, stream>>>(q2, Kp, VpT, clip, Wsl, bsl, multi);
  k_self_attn<<<dim3(35, 24), 256, 0, stream>>>(q2, k2, v2T, hsbuf);

  k_adaptive<<<dim3(512), 256, 0, stream>>>(multi, hsbuf, Wad, bad, blended);
  k_cast<<<dim3(231), 256, 0, stream>>>(hsbuf + (size_t)2048*1536, hstxt, (long)154*1536);

  GOuts oout; oout.C[0] = d_out; oout.C[1] = nullptr; oout.C[2] = nullptr;
  oout.b[0] = bout; oout.b[1] = nullptr; oout.b[2] = nullptr;
  k_gemm<1><<<dim3(12, 16), 256, 0, stream>>>(blended, 1536, WoutT, 1536, oout, 1536, 2048, 1536, 1536);

  GOuts oadd; oadd.C[0] = (float*)d_out + (size_t)2048*1536; oadd.C[1] = nullptr; oadd.C[2] = nullptr;
  oadd.b[0] = badd; oadd.b[1] = nullptr; oadd.b[2] = nullptr;
  k_gemm<1><<<dim3(12, 2), 256, 0, stream>>>(hstxt, 1536, WaddT, 1536, oadd, 1536, 154, 1536, 1536);
}